// Round 6
// baseline (742.300 us; speedup 1.0000x reference)
//
#include <hip/hip_runtime.h>

typedef __attribute__((ext_vector_type(8))) short short8;
typedef __attribute__((ext_vector_type(4))) float f32x4;
typedef unsigned short u16;

#define BB   128
#define SS   256
#define FIN  40
#define HH   64
#define DD   128
#define NHH  4
#define LL   2
#define NEGV (-1e9f)

__device__ __forceinline__ u16 f2b(float f) {
    unsigned u = __float_as_uint(f);
    return (u16)((u + 0x7FFFu + ((u >> 16) & 1u)) >> 16);
}
__device__ __forceinline__ float b2f(u16 u) {
    return __uint_as_float(((unsigned)u) << 16);
}

// ---------------------------------------------------------------- merged fp32 -> bf16 weight convert
__global__ __launch_bounds__(256) void cvt_all_kernel(const float* __restrict__ dm_w,
                                                      const float* __restrict__ ip_w,
                                                      const float* __restrict__ op_w,
                                                      const float* __restrict__ l1_w,
                                                      const float* __restrict__ l2_w,
                                                      u16* __restrict__ o_dm, u16* __restrict__ o_ip,
                                                      u16* __restrict__ o_op, u16* __restrict__ o_l1,
                                                      u16* __restrict__ o_l2) {
    int blk = blockIdx.x;
    const float* s; u16* d; int off;
    if      (blk < 4)   { s = dm_w; d = o_dm; off = blk; }
    else if (blk < 52)  { s = ip_w; d = o_ip; off = blk - 4; }
    else if (blk < 68)  { s = op_w; d = o_op; off = blk - 52; }
    else if (blk < 324) { s = l1_w; d = o_l1; off = blk - 68; }
    else                { s = l2_w; d = o_l2; off = blk - 324; }
    int i = (off * 256 + threadIdx.x) * 8;
    float4 a = *(const float4*)&s[i];
    float4 b = *(const float4*)&s[i + 4];
    short8 o;
    o[0] = (short)f2b(a.x); o[1] = (short)f2b(a.y); o[2] = (short)f2b(a.z); o[3] = (short)f2b(a.w);
    o[4] = (short)f2b(b.x); o[5] = (short)f2b(b.y); o[6] = (short)f2b(b.z); o[7] = (short)f2b(b.w);
    *(short8*)&d[i] = o;
}

// ---------------------------------------------------------------- time mask
__global__ __launch_bounds__(256) void tm_kernel(const float* __restrict__ mask,
                                                 float* __restrict__ tm) {
    int i = blockIdx.x * blockDim.x + threadIdx.x;
    if (i >= BB * SS) return;
    const float* m = mask + (size_t)i * FIN;
    float s = 0.f;
    for (int f = 0; f < FIN; ++f) s += m[f];
    tm[i] = (s > 0.f) ? 1.f : 0.f;
}

// ------------------------------------------------- xw = concat(x,mask,delta) @ W_ih^T + b_ih
#define XW_RPB 16
__global__ __launch_bounds__(192) void xw_kernel(const float* __restrict__ x,
                                                 const float* __restrict__ mask,
                                                 const float* __restrict__ delta,
                                                 const float* __restrict__ w_ih,
                                                 const float* __restrict__ b_ih,
                                                 float* __restrict__ xw) {
    __shared__ float inp[XW_RPB][120];
    __shared__ float wl[192][21];
    int row0 = blockIdx.x * XW_RPB;
    int tid  = threadIdx.x;

    for (int idx = tid; idx < XW_RPB * 120; idx += 192) {
        int r = idx / 120, k = idx % 120;
        int g = row0 + r;
        float v;
        if (k < 40)      v = x[(size_t)g * FIN + k];
        else if (k < 80) v = mask[(size_t)g * FIN + (k - 40)];
        else             v = delta[(size_t)g * FIN + (k - 80)];
        inp[r][k] = v;
    }

    float acc[XW_RPB];
#pragma unroll
    for (int r = 0; r < XW_RPB; ++r) acc[r] = 0.f;

    for (int kt = 0; kt < 6; ++kt) {
        __syncthreads();
        for (int idx = tid; idx < 192 * 20; idx += 192) {
            int r = idx / 20, k = idx % 20;
            wl[r][k] = w_ih[(size_t)r * 120 + kt * 20 + k];
        }
        __syncthreads();
#pragma unroll
        for (int kk = 0; kk < 20; ++kk) {
            float w = wl[tid][kk];
            int kg = kt * 20 + kk;
#pragma unroll
            for (int r = 0; r < XW_RPB; ++r) acc[r] += w * inp[r][kg];
        }
    }
    float bias = b_ih[tid];
    for (int r = 0; r < XW_RPB; ++r)
        xw[(size_t)(row0 + r) * 192 + tid] = acc[r] + bias;
}

// ---------------------------------------------------------------- GRU scan: 3 waves/batch-row
// W_hh lives in LDS, TRANSPOSED: wlds[k][j] so at fixed k the 64 lanes of a wave read
// consecutive words (2 lanes/bank = free). 48KB/step from LDS at 128B/cyc = 384 cyc/step —
// the deterministic fix for R2-R5's register-allocator refusals (spilled weights re-read
// from L2 at ~800 cyc/step). h stays a same-address float4 broadcast (free).
__global__ __launch_bounds__(192, 1) void gru_scan_kernel(const float* __restrict__ w_hh,
                                                          const float* __restrict__ b_hh,
                                                          const float* __restrict__ xw,
                                                          u16* __restrict__ hsb) {
    __shared__ float wlds[64 * 192];   // [k][j]
    __shared__ float h[HH];
    __shared__ float gh[3 * HH];
    __shared__ float xs[3 * HH];
    int b = blockIdx.x, j = threadIdx.x;

    // coalesced global read (j-major), transposed LDS write (one-time; write conflicts ok)
    for (int idx = j; idx < 192 * 64; idx += 192) {
        int row = idx >> 6, k = idx & 63;            // w_hh[row][k]
        wlds[k * 192 + row] = w_hh[idx];
    }

    float bh = b_hh[j];
    if (j < HH) h[j] = 0.f;
    const float* xwb = xw + (size_t)b * SS * 192;
    float xv = xwb[j];
    __syncthreads();

    for (int t = 0; t < SS; ++t) {
        float px = xwb[(size_t)(t + 1 < SS ? t + 1 : t) * 192 + j];   // prefetch next step
        float a0 = bh, a1 = 0.f, a2 = 0.f, a3 = 0.f;   // 4 independent chains
#pragma unroll
        for (int k = 0; k < 64; k += 4) {
            float4 hv = *(const float4*)&h[k];          // broadcast (same addr all lanes)
            float w0 = wlds[(k + 0) * 192 + j];
            float w1 = wlds[(k + 1) * 192 + j];
            float w2 = wlds[(k + 2) * 192 + j];
            float w3 = wlds[(k + 3) * 192 + j];
            a0 += w0 * hv.x; a1 += w1 * hv.y; a2 += w2 * hv.z; a3 += w3 * hv.w;
        }
        gh[j] = (a0 + a1) + (a2 + a3);
        xs[j] = xv;
        __syncthreads();
        if (j < HH) {
            float r  = 1.f / (1.f + __expf(-(xs[j] + gh[j])));
            float zg = 1.f / (1.f + __expf(-(xs[64 + j] + gh[64 + j])));
            float nx = xs[128 + j] + r * gh[128 + j];
            float n  = 2.f / (1.f + __expf(-2.f * nx)) - 1.f;   // tanh
            float hj = (1.f - zg) * n + zg * h[j];
            h[j] = hj;
            hsb[((size_t)b * SS + t) * HH + j] = f2b(hj);
        }
        __syncthreads();
        xv = px;
    }
}

// ---------------------------------------------------------------- bf16 MFMA GEMM (m97 structure)
// MODE: 1=f32 C, 2=bf16 Cb, 3=both, 4=fused residual+LayerNorm (N must be 128, bn==0):
//       z_row = LN(z_old + acc + bias) * ln_s + ln_b  -> C (fp32, in/out) and Cb (bf16)
__device__ __forceinline__ void gl_lds16(const void* g, void* s) {
    __builtin_amdgcn_global_load_lds(
        (const __attribute__((address_space(1))) void*)g,
        (__attribute__((address_space(3))) void*)s, 16, 0, 0);
}

template <int MODE, bool RELU>
__global__ __launch_bounds__(256, 2) void mfma_gemm(const u16* __restrict__ A,
                                                    const u16* __restrict__ W,
                                                    const float* __restrict__ bias,
                                                    float* __restrict__ C,
                                                    u16* __restrict__ Cb,
                                                    const float* __restrict__ lns,
                                                    const float* __restrict__ lnb,
                                                    int M, int N, int K) {
    __shared__ __align__(16) u16 Al[128 * 32];
    __shared__ __align__(16) u16 Bl[128 * 32];
    __shared__ float lred[2][2][128];
    int bm = blockIdx.x, bn = blockIdx.y;
    int tid = threadIdx.x;
    int w = tid >> 6, lane = tid & 63;
    int wrow = (w >> 1) * 64, wcol = (w & 1) * 64;
    int fr = lane & 15, fk = (lane >> 4) * 8;
    int hi = lane >> 4;
    int srow = lane >> 2;
    int scol = (lane & 3) * 8;

    const u16* Ag = A + ((size_t)bm * 128) * K + scol;
    const u16* Wg = W + ((size_t)bn * 128) * K + scol;

    f32x4 acc[4][4];
#pragma unroll
    for (int i = 0; i < 4; ++i)
#pragma unroll
        for (int jj = 0; jj < 4; ++jj) acc[i][jj] = (f32x4){0.f, 0.f, 0.f, 0.f};

    for (int kt = 0; kt < K; kt += 32) {
        __syncthreads();
#pragma unroll
        for (int i = 0; i < 2; ++i) {
            int c = w + i * 4;
            int row = c * 16 + srow;
            gl_lds16(Ag + (size_t)row * K + kt, &Al[c * 512]);
            gl_lds16(Wg + (size_t)row * K + kt, &Bl[c * 512]);
        }
        __syncthreads();
        short8 a[4], bq[4];
#pragma unroll
        for (int m = 0; m < 4; ++m)
            a[m] = *(const short8*)&Al[(wrow + m * 16 + fr) * 32 + fk];
#pragma unroll
        for (int n = 0; n < 4; ++n)
            bq[n] = *(const short8*)&Bl[(wcol + n * 16 + fr) * 32 + fk];
#pragma unroll
        for (int m = 0; m < 4; ++m)
#pragma unroll
            for (int n = 0; n < 4; ++n)
                acc[m][n] = __builtin_amdgcn_mfma_f32_16x16x32_bf16(a[m], bq[n], acc[m][n], 0, 0, 0);
    }

    float bv[4];
#pragma unroll
    for (int n = 0; n < 4; ++n) bv[n] = bias[bn * 128 + wcol + n * 16 + fr];

    if (MODE == 4) {
        // ---- fused residual + LayerNorm (N==128, bn==0) ----
        float v[4][4][4];
#pragma unroll
        for (int m = 0; m < 4; ++m)
#pragma unroll
            for (int j = 0; j < 4; ++j) {
                int row = bm * 128 + wrow + m * 16 + hi * 4 + j;
#pragma unroll
                for (int n = 0; n < 4; ++n)
                    v[m][n][j] = acc[m][n][j] + bv[n] + C[(size_t)row * 128 + wcol + n * 16 + fr];
            }
#pragma unroll
        for (int m = 0; m < 4; ++m)
#pragma unroll
            for (int j = 0; j < 4; ++j) {
                float s = v[m][0][j] + v[m][1][j] + v[m][2][j] + v[m][3][j];
                float q = v[m][0][j]*v[m][0][j] + v[m][1][j]*v[m][1][j]
                        + v[m][2][j]*v[m][2][j] + v[m][3][j]*v[m][3][j];
#pragma unroll
                for (int off = 1; off <= 8; off <<= 1) {
                    s += __shfl_xor(s, off);
                    q += __shfl_xor(q, off);
                }
                if (fr == 0) {
                    int lrow = wrow + m * 16 + hi * 4 + j;
                    lred[0][w & 1][lrow] = s;
                    lred[1][w & 1][lrow] = q;
                }
            }
        __syncthreads();
        float sv[4], bb[4];
#pragma unroll
        for (int n = 0; n < 4; ++n) {
            sv[n] = lns[wcol + n * 16 + fr];
            bb[n] = lnb[wcol + n * 16 + fr];
        }
#pragma unroll
        for (int m = 0; m < 4; ++m)
#pragma unroll
            for (int j = 0; j < 4; ++j) {
                int lrow = wrow + m * 16 + hi * 4 + j;
                float mean = (lred[0][0][lrow] + lred[0][1][lrow]) * (1.f / 128.f);
                float msq  = (lred[1][0][lrow] + lred[1][1][lrow]) * (1.f / 128.f);
                float rstd = rsqrtf(msq - mean * mean + 1e-5f);
                int row = bm * 128 + lrow;
#pragma unroll
                for (int n = 0; n < 4; ++n) {
                    int col = wcol + n * 16 + fr;
                    float o = (v[m][n][j] - mean) * rstd * sv[n] + bb[n];
                    C[(size_t)row * 128 + col] = o;
                    Cb[(size_t)row * 128 + col] = f2b(o);
                }
            }
    } else {
#pragma unroll
        for (int m = 0; m < 4; ++m) {
#pragma unroll
            for (int j = 0; j < 4; ++j) {
                int row = bm * 128 + wrow + m * 16 + hi * 4 + j;
#pragma unroll
                for (int n = 0; n < 4; ++n) {
                    int col = bn * 128 + wcol + n * 16 + fr;
                    float vv = acc[m][n][j] + bv[n];
                    if (RELU) vv = fmaxf(vv, 0.f);
                    if (MODE & 1) C[(size_t)row * N + col] = vv;
                    if (MODE & 2) Cb[(size_t)row * N + col] = f2b(vv);
                }
            }
        }
    }
}

// ---------------------------------------------------------------- attention (bf16 qkv in, bf16 out)
__global__ __launch_bounds__(256) void attn_kernel(const u16* __restrict__ qkv,
                                                   const float* __restrict__ tm,
                                                   u16* __restrict__ attno) {
    int bh = blockIdx.x;
    int b = bh / NHH, hd = bh % NHH;
    int s = threadIdx.x;

    __shared__ float Kt[64][32];
    __shared__ float Vt[64][32];
    __shared__ float tms[64];

    float q[32];
    const u16* qrow = qkv + ((size_t)b * SS + s) * 384 + hd * 32;
#pragma unroll
    for (int j = 0; j < 32; j += 8) {
        short8 v = *(const short8*)&qrow[j];
#pragma unroll
        for (int jj = 0; jj < 8; ++jj) q[j + jj] = b2f((u16)v[jj]);
    }
    const float scale = 0.17677669529663687f;
    float denom = 0.f;
    float o[32];
#pragma unroll
    for (int j = 0; j < 32; ++j) o[j] = 0.f;

    for (int kt = 0; kt < SS; kt += 64) {
        __syncthreads();
        {
            int r = s >> 2, c = (s & 3) * 8;
            const u16* kb = qkv + ((size_t)b * SS + kt + r) * 384 + 128 + hd * 32 + c;
            const u16* vb = qkv + ((size_t)b * SS + kt + r) * 384 + 256 + hd * 32 + c;
            short8 kv = *(const short8*)kb;
            short8 vv = *(const short8*)vb;
#pragma unroll
            for (int jj = 0; jj < 8; ++jj) {
                Kt[r][c + jj] = b2f((u16)kv[jj]);
                Vt[r][c + jj] = b2f((u16)vv[jj]);
            }
        }
        if (s < 64) tms[s] = tm[b * SS + kt + s];
        __syncthreads();
        for (int k = 0; k < 64; ++k) {
            float acc = 0.f;
#pragma unroll
            for (int j = 0; j < 32; ++j) acc += q[j] * Kt[k][j];
            float sc = acc * scale + (tms[k] > 0.f ? 0.f : NEGV);
            float e = __expf(sc);
            denom += e;
#pragma unroll
            for (int j = 0; j < 32; ++j) o[j] += e * Vt[k][j];
        }
    }
    float inv = 1.f / denom;
    u16* orow = attno + ((size_t)b * SS + s) * DD + hd * 32;
#pragma unroll
    for (int j = 0; j < 32; j += 8) {
        short8 ov;
#pragma unroll
        for (int jj = 0; jj < 8; ++jj) ov[jj] = (short)f2b(o[j + jj] * inv);
        *(short8*)&orow[j] = ov;
    }
}

// ---------------------------------------------------------------- score = z @ score_w^T + b (masked)
__global__ __launch_bounds__(256) void score_kernel(const float* __restrict__ z,
                                                    const float* __restrict__ score_w,
                                                    const float* __restrict__ score_b,
                                                    const float* __restrict__ tm,
                                                    float* __restrict__ scores) {
    int row = blockIdx.x * 64 + (threadIdx.x >> 2);
    int c = threadIdx.x & 3;
    const float* zr = z + (size_t)row * DD + c * 32;
    const float* wr = score_w + c * 32;
    float acc = 0.f;
#pragma unroll
    for (int j = 0; j < 32; j += 4) {
        float4 a = *(const float4*)(zr + j), w = *(const float4*)(wr + j);
        acc += a.x * w.x + a.y * w.y + a.z * w.z + a.w * w.w;
    }
    acc += __shfl_xor(acc, 1);
    acc += __shfl_xor(acc, 2);
    if (c == 0) {
        float sc = acc + score_b[0];
        scores[row] = (tm[row] > 0.f) ? sc : NEGV;
    }
}

// ---------------------------------------------------------------- softmax over S + weighted pool
__global__ __launch_bounds__(256) void pool_kernel(const float* __restrict__ z,
                                                   const float* __restrict__ scores,
                                                   float* __restrict__ pooled) {
    int b = blockIdx.x;
    int tid = threadIdx.x;
    __shared__ float al[SS];
    __shared__ float red[8];
    __shared__ float pp[2][128];

    float sc = scores[b * SS + tid];
    float m = sc;
#pragma unroll
    for (int off = 32; off; off >>= 1) m = fmaxf(m, __shfl_xor(m, off));
    if ((tid & 63) == 0) red[tid >> 6] = m;
    __syncthreads();
    m = fmaxf(fmaxf(red[0], red[1]), fmaxf(red[2], red[3]));
    float e = __expf(sc - m);
    float ssum = e;
#pragma unroll
    for (int off = 32; off; off >>= 1) ssum += __shfl_xor(ssum, off);
    if ((tid & 63) == 0) red[4 + (tid >> 6)] = ssum;
    __syncthreads();
    ssum = red[4] + red[5] + red[6] + red[7];
    al[tid] = e / ssum;
    __syncthreads();

    int d = tid & 127, half = tid >> 7;
    float acc = 0.f;
    for (int t = half; t < SS; t += 2) acc += al[t] * z[((size_t)b * SS + t) * DD + d];
    pp[half][d] = acc;
    __syncthreads();
    if (tid < 128) pooled[b * 128 + tid] = pp[0][tid] + pp[1][tid];
}

// ---------------------------------------------------------------- routed heads
__global__ __launch_bounds__(128) void head_kernel(const float* __restrict__ pooled,
                                                   const float* __restrict__ reg_w,
                                                   const float* __restrict__ reg_b,
                                                   const float* __restrict__ bin_w,
                                                   const float* __restrict__ bin_b,
                                                   const int* __restrict__ wid,
                                                   float* __restrict__ out) {
    int b = blockIdx.x, tid = threadIdx.x;
    __shared__ float p[128];
    p[tid] = pooled[b * 128 + tid];
    __syncthreads();
    if (tid < 9) {
        int w = wid[b];
        const float* wrow;
        float bias;
        if (tid < 8) { wrow = reg_w + ((size_t)w * 8 + tid) * 128; bias = reg_b[w * 8 + tid]; }
        else         { wrow = bin_w + (size_t)w * 128;             bias = bin_b[w]; }
        float acc = bias;
        for (int k = 0; k < 128; ++k) acc += wrow[k] * p[k];
        if (tid < 8) out[b * 8 + tid] = acc;
        else         out[1024 + b] = acc;
    }
}

// ================================================================ host
extern "C" void kernel_launch(void* const* d_in, const int* in_sizes, int n_in,
                              void* d_out, int out_size, void* d_ws, size_t ws_size,
                              hipStream_t stream) {
    const float* x         = (const float*)d_in[0];
    const float* mask      = (const float*)d_in[1];
    const float* delta     = (const float*)d_in[2];
    const float* gru_w_ih  = (const float*)d_in[3];
    const float* gru_w_hh  = (const float*)d_in[4];
    const float* gru_b_ih  = (const float*)d_in[5];
    const float* gru_b_hh  = (const float*)d_in[6];
    const float* dm_w      = (const float*)d_in[7];
    const float* dm_b      = (const float*)d_in[8];
    const float* in_proj_w = (const float*)d_in[9];
    const float* in_proj_b = (const float*)d_in[10];
    const float* out_proj_w= (const float*)d_in[11];
    const float* out_proj_b= (const float*)d_in[12];
    const float* lin1_w    = (const float*)d_in[13];
    const float* lin1_b    = (const float*)d_in[14];
    const float* lin2_w    = (const float*)d_in[15];
    const float* lin2_b    = (const float*)d_in[16];
    const float* ln1_s     = (const float*)d_in[17];
    const float* ln1_bb    = (const float*)d_in[18];
    const float* ln2_s     = (const float*)d_in[19];
    const float* ln2_bb    = (const float*)d_in[20];
    const float* score_w   = (const float*)d_in[21];
    const float* score_b   = (const float*)d_in[22];
    const float* reg_w     = (const float*)d_in[23];
    const float* reg_b     = (const float*)d_in[24];
    const float* bin_w     = (const float*)d_in[25];
    const float* bin_b     = (const float*)d_in[26];
    const int*   window_id = (const int*)d_in[27];
    float* out = (float*)d_out;

    char* w8 = (char*)d_ws;
    float* z      = (float*)(w8 + 0);            // 16,777,216
    u16*   zb     = (u16*)  (w8 + 16777216);     //  8,388,608
    u16*   hsb    = (u16*)  (w8 + 25165824);     //  4,194,304
    u16*   wb_dm  = (u16*)  (w8 + 29360128);     //     16,384
    u16*   wb_ip  = (u16*)  (w8 + 29376512);     //    196,608
    u16*   wb_op  = (u16*)  (w8 + 29573120);     //     65,536
    u16*   wb_l1  = (u16*)  (w8 + 29638656);     //  1,048,576
    u16*   wb_l2  = (u16*)  (w8 + 30687232);     //  1,048,576
    float* tm     = (float*)(w8 + 31735808);     //    131,072
    float* scores = (float*)(w8 + 31866880);     //    131,072
    float* pooled = (float*)(w8 + 31997952);     //     65,536
    float* xw     = (float*)(w8 + 32063488);     // 25,165,824 (GRU: xw fp32 | later: qkvb bf16)
    u16*   qkvb   = (u16*)  (w8 + 32063488);
    u16*   ffb    = (u16*)  (w8 + 57229312);     // CH*2048*2 ; attnob aliased at base
    u16*   attnob = ffb;

    int CH = 4096;
    if      (ws_size >= 57229312ull + 134217728ull) CH = 32768;
    else if (ws_size >= 57229312ull +  33554432ull) CH = 8192;
    int nc = 32768 / CH;

    cvt_all_kernel<<<580, 256, 0, stream>>>(dm_w, in_proj_w, out_proj_w, lin1_w, lin2_w,
                                            wb_dm, wb_ip, wb_op, wb_l1, wb_l2);

    tm_kernel<<<(BB * SS + 255) / 256, 256, 0, stream>>>(mask, tm);
    xw_kernel<<<BB * SS / XW_RPB, 192, 0, stream>>>(x, mask, delta, gru_w_ih, gru_b_ih, xw);
    gru_scan_kernel<<<BB, 192, 0, stream>>>(gru_w_hh, gru_b_hh, xw, hsb);

    mfma_gemm<3, false><<<dim3(256, 1), 256, 0, stream>>>(
        hsb, wb_dm, dm_b, z, zb, nullptr, nullptr, 32768, 128, 64);

    for (int l = 0; l < LL; ++l) {
        mfma_gemm<2, false><<<dim3(256, 3), 256, 0, stream>>>(
            zb, wb_ip + (size_t)l * 49152, in_proj_b + l * 384, nullptr, qkvb,
            nullptr, nullptr, 32768, 384, 128);
        attn_kernel<<<BB * NHH, 256, 0, stream>>>(qkvb, tm, attnob);
        // out_proj + residual + LN1 fused
        mfma_gemm<4, false><<<dim3(256, 1), 256, 0, stream>>>(
            attnob, wb_op + (size_t)l * 16384, out_proj_b + l * 128, z, zb,
            ln1_s + l * 128, ln1_bb + l * 128, 32768, 128, 128);
        for (int c = 0; c < nc; ++c) {
            mfma_gemm<2, true><<<dim3(CH / 128, 16), 256, 0, stream>>>(
                zb + (size_t)c * CH * 128, wb_l1 + (size_t)l * 262144, lin1_b + l * 2048,
                nullptr, ffb, nullptr, nullptr, CH, 2048, 128);
            // lin2 + residual + LN2 fused
            mfma_gemm<4, false><<<dim3(CH / 128, 1), 256, 0, stream>>>(
                ffb, wb_l2 + (size_t)l * 262144, lin2_b + l * 128,
                z + (size_t)c * CH * 128, zb + (size_t)c * CH * 128,
                ln2_s + l * 128, ln2_bb + l * 128, CH, 128, 2048);
        }
    }

    score_kernel<<<BB * SS / 64, 256, 0, stream>>>(z, score_w, score_b, tm, scores);
    pool_kernel<<<BB, 256, 0, stream>>>(z, scores, pooled);
    head_kernel<<<BB, 128, 0, stream>>>(pooled, reg_w, reg_b, bin_w, bin_b, window_id, out);
}

// Round 7
// 704.491 us; speedup vs baseline: 1.0537x; 1.0537x over previous
//
#include <hip/hip_runtime.h>

typedef __attribute__((ext_vector_type(8))) short short8;
typedef __attribute__((ext_vector_type(4))) float f32x4;
typedef unsigned short u16;

#define BB   128
#define SS   256
#define FIN  40
#define HH   64
#define DD   128
#define NHH  4
#define LL   2
#define NEGV (-1e9f)

__device__ __forceinline__ u16 f2b(float f) {
    unsigned u = __float_as_uint(f);
    return (u16)((u + 0x7FFFu + ((u >> 16) & 1u)) >> 16);
}
__device__ __forceinline__ float b2f(u16 u) {
    return __uint_as_float(((unsigned)u) << 16);
}

// ---------------------------------------------------------------- merged fp32 -> bf16 weight convert
__global__ __launch_bounds__(256) void cvt_all_kernel(const float* __restrict__ dm_w,
                                                      const float* __restrict__ ip_w,
                                                      const float* __restrict__ op_w,
                                                      const float* __restrict__ l1_w,
                                                      const float* __restrict__ l2_w,
                                                      u16* __restrict__ o_dm, u16* __restrict__ o_ip,
                                                      u16* __restrict__ o_op, u16* __restrict__ o_l1,
                                                      u16* __restrict__ o_l2) {
    int blk = blockIdx.x;
    const float* s; u16* d; int off;
    if      (blk < 4)   { s = dm_w; d = o_dm; off = blk; }
    else if (blk < 52)  { s = ip_w; d = o_ip; off = blk - 4; }
    else if (blk < 68)  { s = op_w; d = o_op; off = blk - 52; }
    else if (blk < 324) { s = l1_w; d = o_l1; off = blk - 68; }
    else                { s = l2_w; d = o_l2; off = blk - 324; }
    int i = (off * 256 + threadIdx.x) * 8;
    float4 a = *(const float4*)&s[i];
    float4 b = *(const float4*)&s[i + 4];
    short8 o;
    o[0] = (short)f2b(a.x); o[1] = (short)f2b(a.y); o[2] = (short)f2b(a.z); o[3] = (short)f2b(a.w);
    o[4] = (short)f2b(b.x); o[5] = (short)f2b(b.y); o[6] = (short)f2b(b.z); o[7] = (short)f2b(b.w);
    *(short8*)&d[i] = o;
}

// ---------------------------------------------------------------- time mask
__global__ __launch_bounds__(256) void tm_kernel(const float* __restrict__ mask,
                                                 float* __restrict__ tm) {
    int i = blockIdx.x * blockDim.x + threadIdx.x;
    if (i >= BB * SS) return;
    const float* m = mask + (size_t)i * FIN;
    float s = 0.f;
    for (int f = 0; f < FIN; ++f) s += m[f];
    tm[i] = (s > 0.f) ? 1.f : 0.f;
}

// ------------------------------------------------- xw = concat(x,mask,delta) @ W_ih^T + b_ih
#define XW_RPB 16
__global__ __launch_bounds__(192) void xw_kernel(const float* __restrict__ x,
                                                 const float* __restrict__ mask,
                                                 const float* __restrict__ delta,
                                                 const float* __restrict__ w_ih,
                                                 const float* __restrict__ b_ih,
                                                 float* __restrict__ xw) {
    __shared__ float inp[XW_RPB][120];
    __shared__ float wl[192][21];
    int row0 = blockIdx.x * XW_RPB;
    int tid  = threadIdx.x;

    for (int idx = tid; idx < XW_RPB * 120; idx += 192) {
        int r = idx / 120, k = idx % 120;
        int g = row0 + r;
        float v;
        if (k < 40)      v = x[(size_t)g * FIN + k];
        else if (k < 80) v = mask[(size_t)g * FIN + (k - 40)];
        else             v = delta[(size_t)g * FIN + (k - 80)];
        inp[r][k] = v;
    }

    float acc[XW_RPB];
#pragma unroll
    for (int r = 0; r < XW_RPB; ++r) acc[r] = 0.f;

    for (int kt = 0; kt < 6; ++kt) {
        __syncthreads();
        for (int idx = tid; idx < 192 * 20; idx += 192) {
            int r = idx / 20, k = idx % 20;
            wl[r][k] = w_ih[(size_t)r * 120 + kt * 20 + k];
        }
        __syncthreads();
#pragma unroll
        for (int kk = 0; kk < 20; ++kk) {
            float w = wl[tid][kk];
            int kg = kt * 20 + kk;
#pragma unroll
            for (int r = 0; r < XW_RPB; ++r) acc[r] += w * inp[r][kg];
        }
    }
    float bias = b_ih[tid];
    for (int r = 0; r < XW_RPB; ++r)
        xw[(size_t)(row0 + r) * 192 + tid] = acc[r] + bias;
}

// ---------------------------------------------------------------- GRU scan: 3 waves/batch-row
// W_hh in LDS as float4 [kc 0..15][row 0..191]: per step each thread issues 16 ds_read_b128
// (not 64 b32 -> 4x fewer lgkm waits, results fit VGPRs, contiguous 1KB/wave-read = no bank
// conflicts; init write same pattern = conflict-free, fixing R6's 1.5M-conflict init).
__global__ __launch_bounds__(192, 1) void gru_scan_kernel(const float* __restrict__ w_hh,
                                                          const float* __restrict__ b_hh,
                                                          const float* __restrict__ xw,
                                                          u16* __restrict__ hsb) {
    __shared__ float4 wlds4[16 * 192];   // [kc][row]  48KB
    __shared__ float h[HH];
    __shared__ float gh[3 * HH];
    __shared__ float xs[3 * HH];
    int b = blockIdx.x, j = threadIdx.x;

    {
        const float4* pw = (const float4*)(w_hh + (size_t)j * HH);
#pragma unroll
        for (int kc = 0; kc < 16; ++kc) wlds4[kc * 192 + j] = pw[kc];
    }

    float bh = b_hh[j];
    if (j < HH) h[j] = 0.f;
    const float* xwb = xw + (size_t)b * SS * 192;
    float xv = xwb[j];
    __syncthreads();

    for (int t = 0; t < SS; ++t) {
        float px = xwb[(size_t)(t + 1 < SS ? t + 1 : t) * 192 + j];   // prefetch next step
        float a0 = 0.f, a1 = 0.f, a2 = 0.f, a3 = 0.f;   // 4 chains, kc round-robin
#pragma unroll
        for (int kc = 0; kc < 16; kc += 4) {
            float4 w0 = wlds4[(kc + 0) * 192 + j];
            float4 w1 = wlds4[(kc + 1) * 192 + j];
            float4 w2 = wlds4[(kc + 2) * 192 + j];
            float4 w3 = wlds4[(kc + 3) * 192 + j];
            float4 h0 = *(const float4*)&h[(kc + 0) * 4];   // broadcast
            float4 h1 = *(const float4*)&h[(kc + 1) * 4];
            float4 h2 = *(const float4*)&h[(kc + 2) * 4];
            float4 h3 = *(const float4*)&h[(kc + 3) * 4];
            a0 += w0.x*h0.x + w0.y*h0.y + w0.z*h0.z + w0.w*h0.w;
            a1 += w1.x*h1.x + w1.y*h1.y + w1.z*h1.z + w1.w*h1.w;
            a2 += w2.x*h2.x + w2.y*h2.y + w2.z*h2.z + w2.w*h2.w;
            a3 += w3.x*h3.x + w3.y*h3.y + w3.z*h3.z + w3.w*h3.w;
        }
        gh[j] = ((a0 + a1) + (a2 + a3)) + bh;
        xs[j] = xv;
        __syncthreads();
        if (j < HH) {
            float r  = 1.f / (1.f + __expf(-(xs[j] + gh[j])));
            float zg = 1.f / (1.f + __expf(-(xs[64 + j] + gh[64 + j])));
            float nx = xs[128 + j] + r * gh[128 + j];
            float n  = 2.f / (1.f + __expf(-2.f * nx)) - 1.f;   // tanh
            float hj = (1.f - zg) * n + zg * h[j];
            h[j] = hj;
            hsb[((size_t)b * SS + t) * HH + j] = f2b(hj);
        }
        __syncthreads();
        xv = px;
    }
}

// ---------------------------------------------------------------- bf16 MFMA GEMM
// BK=64, LDS rows of 128B with XOR slot swizzle (T2, rule 21: linear gl_lds dest +
// pre-swizzled global source + swizzled ds_read). Frag reads: 2 lanes/bank = free.
// MODE: 1=f32 C, 2=bf16 Cb, 3=both, 4=fused residual+LayerNorm (N==128, bn==0)
__device__ __forceinline__ void gl_lds16(const void* g, void* s) {
    __builtin_amdgcn_global_load_lds(
        (const __attribute__((address_space(1))) void*)g,
        (__attribute__((address_space(3))) void*)s, 16, 0, 0);
}

template <int MODE, bool RELU>
__global__ __launch_bounds__(256, 2) void mfma_gemm(const u16* __restrict__ A,
                                                    const u16* __restrict__ W,
                                                    const float* __restrict__ bias,
                                                    float* __restrict__ C,
                                                    u16* __restrict__ Cb,
                                                    const float* __restrict__ lns,
                                                    const float* __restrict__ lnb,
                                                    int M, int N, int K) {
    __shared__ __align__(16) u16 Al[128 * 64];   // 16KB each
    __shared__ __align__(16) u16 Bl[128 * 64];
    __shared__ float lred[2][2][128];
    int bm = blockIdx.x, bn = blockIdx.y;
    int tid = threadIdx.x;
    int w = tid >> 6, lane = tid & 63;
    int wrow = (w >> 1) * 64, wcol = (w & 1) * 64;
    int fr = lane & 15, hi = lane >> 4;
    int rl = lane >> 3;          // staging: row within 8-row chunk
    int sl = lane & 7;           // staging: dest slot (16B units)
    int ssl = sl ^ rl;           // pre-swizzled source slot

    const u16* Ag = A + ((size_t)bm * 128) * K + ssl * 8;
    const u16* Wg = W + ((size_t)bn * 128) * K + ssl * 8;

    f32x4 acc[4][4];
#pragma unroll
    for (int i = 0; i < 4; ++i)
#pragma unroll
        for (int jj = 0; jj < 4; ++jj) acc[i][jj] = (f32x4){0.f, 0.f, 0.f, 0.f};

    // per-lane swizzled read offsets (u16 units): row r, slot s -> r*64 + ((s ^ (r&7))*8)
    int ar[4], br[4];
#pragma unroll
    for (int m = 0; m < 4; ++m) {
        int r = wrow + m * 16 + fr;
        ar[m] = r * 64;
        r = wcol + m * 16 + fr;
        br[m] = r * 64;
    }
    int swz = (fr & 7);          // row&7 for both a and b rows (wrow,wcol,m*16 are mult of 8... 16)

    for (int kt = 0; kt < K; kt += 64) {
        __syncthreads();
#pragma unroll
        for (int i = 0; i < 4; ++i) {
            int c = w * 4 + i;               // chunk 0..15, 8 rows each
            int row = c * 8 + rl;
            gl_lds16(Ag + (size_t)row * K + kt, &Al[c * 512]);
            gl_lds16(Wg + (size_t)row * K + kt, &Bl[c * 512]);
        }
        __syncthreads();
#pragma unroll
        for (int kk = 0; kk < 2; ++kk) {
            short8 a[4], bq[4];
            int slot = kk * 4 + hi;
            int soff = ((slot ^ swz) << 3);
#pragma unroll
            for (int m = 0; m < 4; ++m)
                a[m] = *(const short8*)&Al[ar[m] + soff];
#pragma unroll
            for (int n = 0; n < 4; ++n)
                bq[n] = *(const short8*)&Bl[br[n] + soff];
#pragma unroll
            for (int m = 0; m < 4; ++m)
#pragma unroll
                for (int n = 0; n < 4; ++n)
                    acc[m][n] = __builtin_amdgcn_mfma_f32_16x16x32_bf16(a[m], bq[n], acc[m][n], 0, 0, 0);
        }
    }

    float bv[4];
#pragma unroll
    for (int n = 0; n < 4; ++n) bv[n] = bias[bn * 128 + wcol + n * 16 + fr];

    if (MODE == 4) {
        // ---- fused residual + LayerNorm (N==128, bn==0) ----
        float v[4][4][4];
#pragma unroll
        for (int m = 0; m < 4; ++m)
#pragma unroll
            for (int j = 0; j < 4; ++j) {
                int row = bm * 128 + wrow + m * 16 + hi * 4 + j;
#pragma unroll
                for (int n = 0; n < 4; ++n)
                    v[m][n][j] = acc[m][n][j] + bv[n] + C[(size_t)row * 128 + wcol + n * 16 + fr];
            }
#pragma unroll
        for (int m = 0; m < 4; ++m)
#pragma unroll
            for (int j = 0; j < 4; ++j) {
                float s = v[m][0][j] + v[m][1][j] + v[m][2][j] + v[m][3][j];
                float q = v[m][0][j]*v[m][0][j] + v[m][1][j]*v[m][1][j]
                        + v[m][2][j]*v[m][2][j] + v[m][3][j]*v[m][3][j];
#pragma unroll
                for (int off = 1; off <= 8; off <<= 1) {
                    s += __shfl_xor(s, off);
                    q += __shfl_xor(q, off);
                }
                if (fr == 0) {
                    int lrow = wrow + m * 16 + hi * 4 + j;
                    lred[0][w & 1][lrow] = s;
                    lred[1][w & 1][lrow] = q;
                }
            }
        __syncthreads();
        float sv[4], bb[4];
#pragma unroll
        for (int n = 0; n < 4; ++n) {
            sv[n] = lns[wcol + n * 16 + fr];
            bb[n] = lnb[wcol + n * 16 + fr];
        }
#pragma unroll
        for (int m = 0; m < 4; ++m)
#pragma unroll
            for (int j = 0; j < 4; ++j) {
                int lrow = wrow + m * 16 + hi * 4 + j;
                float mean = (lred[0][0][lrow] + lred[0][1][lrow]) * (1.f / 128.f);
                float msq  = (lred[1][0][lrow] + lred[1][1][lrow]) * (1.f / 128.f);
                float rstd = rsqrtf(msq - mean * mean + 1e-5f);
                int row = bm * 128 + lrow;
#pragma unroll
                for (int n = 0; n < 4; ++n) {
                    int col = wcol + n * 16 + fr;
                    float o = (v[m][n][j] - mean) * rstd * sv[n] + bb[n];
                    C[(size_t)row * 128 + col] = o;
                    Cb[(size_t)row * 128 + col] = f2b(o);
                }
            }
    } else {
#pragma unroll
        for (int m = 0; m < 4; ++m) {
#pragma unroll
            for (int j = 0; j < 4; ++j) {
                int row = bm * 128 + wrow + m * 16 + hi * 4 + j;
#pragma unroll
                for (int n = 0; n < 4; ++n) {
                    int col = bn * 128 + wcol + n * 16 + fr;
                    float vv = acc[m][n][j] + bv[n];
                    if (RELU) vv = fmaxf(vv, 0.f);
                    if (MODE & 1) C[(size_t)row * N + col] = vv;
                    if (MODE & 2) Cb[(size_t)row * N + col] = f2b(vv);
                }
            }
        }
    }
}

// ---------------------------------------------------------------- attention (bf16 qkv in, bf16 out)
__global__ __launch_bounds__(256) void attn_kernel(const u16* __restrict__ qkv,
                                                   const float* __restrict__ tm,
                                                   u16* __restrict__ attno) {
    int bh = blockIdx.x;
    int b = bh / NHH, hd = bh % NHH;
    int s = threadIdx.x;

    __shared__ float Kt[64][32];
    __shared__ float Vt[64][32];
    __shared__ float tms[64];

    float q[32];
    const u16* qrow = qkv + ((size_t)b * SS + s) * 384 + hd * 32;
#pragma unroll
    for (int j = 0; j < 32; j += 8) {
        short8 v = *(const short8*)&qrow[j];
#pragma unroll
        for (int jj = 0; jj < 8; ++jj) q[j + jj] = b2f((u16)v[jj]);
    }
    const float scale = 0.17677669529663687f;
    float denom = 0.f;
    float o[32];
#pragma unroll
    for (int j = 0; j < 32; ++j) o[j] = 0.f;

    for (int kt = 0; kt < SS; kt += 64) {
        __syncthreads();
        {
            int r = s >> 2, c = (s & 3) * 8;
            const u16* kb = qkv + ((size_t)b * SS + kt + r) * 384 + 128 + hd * 32 + c;
            const u16* vb = qkv + ((size_t)b * SS + kt + r) * 384 + 256 + hd * 32 + c;
            short8 kv = *(const short8*)kb;
            short8 vv = *(const short8*)vb;
#pragma unroll
            for (int jj = 0; jj < 8; ++jj) {
                Kt[r][c + jj] = b2f((u16)kv[jj]);
                Vt[r][c + jj] = b2f((u16)vv[jj]);
            }
        }
        if (s < 64) tms[s] = tm[b * SS + kt + s];
        __syncthreads();
        for (int k = 0; k < 64; ++k) {
            float acc = 0.f;
#pragma unroll
            for (int j = 0; j < 32; ++j) acc += q[j] * Kt[k][j];
            float sc = acc * scale + (tms[k] > 0.f ? 0.f : NEGV);
            float e = __expf(sc);
            denom += e;
#pragma unroll
            for (int j = 0; j < 32; ++j) o[j] += e * Vt[k][j];
        }
    }
    float inv = 1.f / denom;
    u16* orow = attno + ((size_t)b * SS + s) * DD + hd * 32;
#pragma unroll
    for (int j = 0; j < 32; j += 8) {
        short8 ov;
#pragma unroll
        for (int jj = 0; jj < 8; ++jj) ov[jj] = (short)f2b(o[j + jj] * inv);
        *(short8*)&orow[j] = ov;
    }
}

// ---------------------------------------------------------------- score = z @ score_w^T + b (masked)
__global__ __launch_bounds__(256) void score_kernel(const float* __restrict__ z,
                                                    const float* __restrict__ score_w,
                                                    const float* __restrict__ score_b,
                                                    const float* __restrict__ tm,
                                                    float* __restrict__ scores) {
    int row = blockIdx.x * 64 + (threadIdx.x >> 2);
    int c = threadIdx.x & 3;
    const float* zr = z + (size_t)row * DD + c * 32;
    const float* wr = score_w + c * 32;
    float acc = 0.f;
#pragma unroll
    for (int j = 0; j < 32; j += 4) {
        float4 a = *(const float4*)(zr + j), w = *(const float4*)(wr + j);
        acc += a.x * w.x + a.y * w.y + a.z * w.z + a.w * w.w;
    }
    acc += __shfl_xor(acc, 1);
    acc += __shfl_xor(acc, 2);
    if (c == 0) {
        float sc = acc + score_b[0];
        scores[row] = (tm[row] > 0.f) ? sc : NEGV;
    }
}

// ---------------------------------------------------------------- softmax over S + weighted pool
__global__ __launch_bounds__(256) void pool_kernel(const float* __restrict__ z,
                                                   const float* __restrict__ scores,
                                                   float* __restrict__ pooled) {
    int b = blockIdx.x;
    int tid = threadIdx.x;
    __shared__ float al[SS];
    __shared__ float red[8];
    __shared__ float pp[2][128];

    float sc = scores[b * SS + tid];
    float m = sc;
#pragma unroll
    for (int off = 32; off; off >>= 1) m = fmaxf(m, __shfl_xor(m, off));
    if ((tid & 63) == 0) red[tid >> 6] = m;
    __syncthreads();
    m = fmaxf(fmaxf(red[0], red[1]), fmaxf(red[2], red[3]));
    float e = __expf(sc - m);
    float ssum = e;
#pragma unroll
    for (int off = 32; off; off >>= 1) ssum += __shfl_xor(ssum, off);
    if ((tid & 63) == 0) red[4 + (tid >> 6)] = ssum;
    __syncthreads();
    ssum = red[4] + red[5] + red[6] + red[7];
    al[tid] = e / ssum;
    __syncthreads();

    int d = tid & 127, half = tid >> 7;
    float acc = 0.f;
    for (int t = half; t < SS; t += 2) acc += al[t] * z[((size_t)b * SS + t) * DD + d];
    pp[half][d] = acc;
    __syncthreads();
    if (tid < 128) pooled[b * 128 + tid] = pp[0][tid] + pp[1][tid];
}

// ---------------------------------------------------------------- routed heads
__global__ __launch_bounds__(128) void head_kernel(const float* __restrict__ pooled,
                                                   const float* __restrict__ reg_w,
                                                   const float* __restrict__ reg_b,
                                                   const float* __restrict__ bin_w,
                                                   const float* __restrict__ bin_b,
                                                   const int* __restrict__ wid,
                                                   float* __restrict__ out) {
    int b = blockIdx.x, tid = threadIdx.x;
    __shared__ float p[128];
    p[tid] = pooled[b * 128 + tid];
    __syncthreads();
    if (tid < 9) {
        int w = wid[b];
        const float* wrow;
        float bias;
        if (tid < 8) { wrow = reg_w + ((size_t)w * 8 + tid) * 128; bias = reg_b[w * 8 + tid]; }
        else         { wrow = bin_w + (size_t)w * 128;             bias = bin_b[w]; }
        float acc = bias;
        for (int k = 0; k < 128; ++k) acc += wrow[k] * p[k];
        if (tid < 8) out[b * 8 + tid] = acc;
        else         out[1024 + b] = acc;
    }
}

// ================================================================ host
extern "C" void kernel_launch(void* const* d_in, const int* in_sizes, int n_in,
                              void* d_out, int out_size, void* d_ws, size_t ws_size,
                              hipStream_t stream) {
    const float* x         = (const float*)d_in[0];
    const float* mask      = (const float*)d_in[1];
    const float* delta     = (const float*)d_in[2];
    const float* gru_w_ih  = (const float*)d_in[3];
    const float* gru_w_hh  = (const float*)d_in[4];
    const float* gru_b_ih  = (const float*)d_in[5];
    const float* gru_b_hh  = (const float*)d_in[6];
    const float* dm_w      = (const float*)d_in[7];
    const float* dm_b      = (const float*)d_in[8];
    const float* in_proj_w = (const float*)d_in[9];
    const float* in_proj_b = (const float*)d_in[10];
    const float* out_proj_w= (const float*)d_in[11];
    const float* out_proj_b= (const float*)d_in[12];
    const float* lin1_w    = (const float*)d_in[13];
    const float* lin1_b    = (const float*)d_in[14];
    const float* lin2_w    = (const float*)d_in[15];
    const float* lin2_b    = (const float*)d_in[16];
    const float* ln1_s     = (const float*)d_in[17];
    const float* ln1_bb    = (const float*)d_in[18];
    const float* ln2_s     = (const float*)d_in[19];
    const float* ln2_bb    = (const float*)d_in[20];
    const float* score_w   = (const float*)d_in[21];
    const float* score_b   = (const float*)d_in[22];
    const float* reg_w     = (const float*)d_in[23];
    const float* reg_b     = (const float*)d_in[24];
    const float* bin_w     = (const float*)d_in[25];
    const float* bin_b     = (const float*)d_in[26];
    const int*   window_id = (const int*)d_in[27];
    float* out = (float*)d_out;

    char* w8 = (char*)d_ws;
    float* z      = (float*)(w8 + 0);            // 16,777,216
    u16*   zb     = (u16*)  (w8 + 16777216);     //  8,388,608
    u16*   hsb    = (u16*)  (w8 + 25165824);     //  4,194,304
    u16*   wb_dm  = (u16*)  (w8 + 29360128);     //     16,384
    u16*   wb_ip  = (u16*)  (w8 + 29376512);     //    196,608
    u16*   wb_op  = (u16*)  (w8 + 29573120);     //     65,536
    u16*   wb_l1  = (u16*)  (w8 + 29638656);     //  1,048,576
    u16*   wb_l2  = (u16*)  (w8 + 30687232);     //  1,048,576
    float* tm     = (float*)(w8 + 31735808);     //    131,072
    float* scores = (float*)(w8 + 31866880);     //    131,072
    float* pooled = (float*)(w8 + 31997952);     //     65,536
    float* xw     = (float*)(w8 + 32063488);     // 25,165,824 (GRU: xw fp32 | later: qkvb bf16)
    u16*   qkvb   = (u16*)  (w8 + 32063488);
    u16*   ffb    = (u16*)  (w8 + 57229312);     // CH*2048*2 ; attnob aliased at base
    u16*   attnob = ffb;

    int CH = 4096;
    if      (ws_size >= 57229312ull + 134217728ull) CH = 32768;
    else if (ws_size >= 57229312ull +  33554432ull) CH = 8192;
    int nc = 32768 / CH;

    cvt_all_kernel<<<580, 256, 0, stream>>>(dm_w, in_proj_w, out_proj_w, lin1_w, lin2_w,
                                            wb_dm, wb_ip, wb_op, wb_l1, wb_l2);

    tm_kernel<<<(BB * SS + 255) / 256, 256, 0, stream>>>(mask, tm);
    xw_kernel<<<BB * SS / XW_RPB, 192, 0, stream>>>(x, mask, delta, gru_w_ih, gru_b_ih, xw);
    gru_scan_kernel<<<BB, 192, 0, stream>>>(gru_w_hh, gru_b_hh, xw, hsb);

    mfma_gemm<3, false><<<dim3(256, 1), 256, 0, stream>>>(
        hsb, wb_dm, dm_b, z, zb, nullptr, nullptr, 32768, 128, 64);

    for (int l = 0; l < LL; ++l) {
        mfma_gemm<2, false><<<dim3(256, 3), 256, 0, stream>>>(
            zb, wb_ip + (size_t)l * 49152, in_proj_b + l * 384, nullptr, qkvb,
            nullptr, nullptr, 32768, 384, 128);
        attn_kernel<<<BB * NHH, 256, 0, stream>>>(qkvb, tm, attnob);
        // out_proj + residual + LN1 fused
        mfma_gemm<4, false><<<dim3(256, 1), 256, 0, stream>>>(
            attnob, wb_op + (size_t)l * 16384, out_proj_b + l * 128, z, zb,
            ln1_s + l * 128, ln1_bb + l * 128, 32768, 128, 128);
        for (int c = 0; c < nc; ++c) {
            mfma_gemm<2, true><<<dim3(CH / 128, 16), 256, 0, stream>>>(
                zb + (size_t)c * CH * 128, wb_l1 + (size_t)l * 262144, lin1_b + l * 2048,
                nullptr, ffb, nullptr, nullptr, CH, 2048, 128);
            // lin2 + residual + LN2 fused
            mfma_gemm<4, false><<<dim3(CH / 128, 1), 256, 0, stream>>>(
                ffb, wb_l2 + (size_t)l * 262144, lin2_b + l * 128,
                z + (size_t)c * CH * 128, zb + (size_t)c * CH * 128,
                ln2_s + l * 128, ln2_bb + l * 128, CH, 128, 2048);
        }
    }

    score_kernel<<<BB * SS / 64, 256, 0, stream>>>(z, score_w, score_b, tm, scores);
    pool_kernel<<<BB, 256, 0, stream>>>(z, scores, pooled);
    head_kernel<<<BB, 128, 0, stream>>>(pooled, reg_w, reg_b, bin_w, bin_b, window_id, out);
}

// Round 8
// 695.182 us; speedup vs baseline: 1.0678x; 1.0134x over previous
//
#include <hip/hip_runtime.h>

typedef __attribute__((ext_vector_type(8))) short short8;
typedef __attribute__((ext_vector_type(4))) float f32x4;
typedef unsigned short u16;

#define BB   128
#define SS   256
#define FIN  40
#define HH   64
#define DD   128
#define NHH  4
#define LL   2
#define NEGV (-1e9f)

__device__ __forceinline__ u16 f2b(float f) {
    unsigned u = __float_as_uint(f);
    return (u16)((u + 0x7FFFu + ((u >> 16) & 1u)) >> 16);
}
__device__ __forceinline__ float b2f(u16 u) {
    return __uint_as_float(((unsigned)u) << 16);
}

// ---------------------------------------------------------------- merged fp32 -> bf16 weight convert
__global__ __launch_bounds__(256) void cvt_all_kernel(const float* __restrict__ dm_w,
                                                      const float* __restrict__ ip_w,
                                                      const float* __restrict__ op_w,
                                                      const float* __restrict__ l1_w,
                                                      const float* __restrict__ l2_w,
                                                      u16* __restrict__ o_dm, u16* __restrict__ o_ip,
                                                      u16* __restrict__ o_op, u16* __restrict__ o_l1,
                                                      u16* __restrict__ o_l2) {
    int blk = blockIdx.x;
    const float* s; u16* d; int off;
    if      (blk < 4)   { s = dm_w; d = o_dm; off = blk; }
    else if (blk < 52)  { s = ip_w; d = o_ip; off = blk - 4; }
    else if (blk < 68)  { s = op_w; d = o_op; off = blk - 52; }
    else if (blk < 324) { s = l1_w; d = o_l1; off = blk - 68; }
    else                { s = l2_w; d = o_l2; off = blk - 324; }
    int i = (off * 256 + threadIdx.x) * 8;
    float4 a = *(const float4*)&s[i];
    float4 b = *(const float4*)&s[i + 4];
    short8 o;
    o[0] = (short)f2b(a.x); o[1] = (short)f2b(a.y); o[2] = (short)f2b(a.z); o[3] = (short)f2b(a.w);
    o[4] = (short)f2b(b.x); o[5] = (short)f2b(b.y); o[6] = (short)f2b(b.z); o[7] = (short)f2b(b.w);
    *(short8*)&d[i] = o;
}

// ---------------------------------------------------------------- time mask
__global__ __launch_bounds__(256) void tm_kernel(const float* __restrict__ mask,
                                                 float* __restrict__ tm) {
    int i = blockIdx.x * blockDim.x + threadIdx.x;
    if (i >= BB * SS) return;
    const float* m = mask + (size_t)i * FIN;
    float s = 0.f;
    for (int f = 0; f < FIN; ++f) s += m[f];
    tm[i] = (s > 0.f) ? 1.f : 0.f;
}

// ------------------------------------------------- xw = concat(x,mask,delta) @ W_ih^T + b_ih
#define XW_RPB 16
__global__ __launch_bounds__(192) void xw_kernel(const float* __restrict__ x,
                                                 const float* __restrict__ mask,
                                                 const float* __restrict__ delta,
                                                 const float* __restrict__ w_ih,
                                                 const float* __restrict__ b_ih,
                                                 float* __restrict__ xw) {
    __shared__ float inp[XW_RPB][120];
    __shared__ float wl[192][21];
    int row0 = blockIdx.x * XW_RPB;
    int tid  = threadIdx.x;

    for (int idx = tid; idx < XW_RPB * 120; idx += 192) {
        int r = idx / 120, k = idx % 120;
        int g = row0 + r;
        float v;
        if (k < 40)      v = x[(size_t)g * FIN + k];
        else if (k < 80) v = mask[(size_t)g * FIN + (k - 40)];
        else             v = delta[(size_t)g * FIN + (k - 80)];
        inp[r][k] = v;
    }

    float acc[XW_RPB];
#pragma unroll
    for (int r = 0; r < XW_RPB; ++r) acc[r] = 0.f;

    for (int kt = 0; kt < 6; ++kt) {
        __syncthreads();
        for (int idx = tid; idx < 192 * 20; idx += 192) {
            int r = idx / 20, k = idx % 20;
            wl[r][k] = w_ih[(size_t)r * 120 + kt * 20 + k];
        }
        __syncthreads();
#pragma unroll
        for (int kk = 0; kk < 20; ++kk) {
            float w = wl[tid][kk];
            int kg = kt * 20 + kk;
#pragma unroll
            for (int r = 0; r < XW_RPB; ++r) acc[r] += w * inp[r][kg];
        }
    }
    float bias = b_ih[tid];
    for (int r = 0; r < XW_RPB; ++r)
        xw[(size_t)(row0 + r) * 192 + tid] = acc[r] + bias;
}

// ---------------------------------------------------------------- MFMA GRU scan
// 8 blocks x 16 batch rows, 4 waves. W_hh bf16 as swizzled B-frag source in LDS (24KB);
// h: fp32 master (hf, per-lane owned) + bf16 A-frag copy double-buffered (hb).
// Per step/wave: 7 ds_read_b128 + 6 MFMA + gate VALU; ONE barrier per step.
// Wave w owns gate cols c = w*16 + (lane&15) for all 3 gates (N-tiles {w,w+4,w+8});
// C layout: lane holds rows rb = (lane>>4)*4 + j at its col c.
__global__ __launch_bounds__(256, 1) void gru_scan_kernel(const float* __restrict__ w_hh,
                                                          const float* __restrict__ b_hh,
                                                          const float* __restrict__ xw,
                                                          u16* __restrict__ hsb) {
    __shared__ __align__(16) u16 wl[192 * 64];     // [gate_row][k], slot^(row&7) swizzled
    __shared__ __align__(16) u16 hb[2][16 * 64];   // bf16 h, same swizzle
    __shared__ float hf[16 * 64];                  // fp32 h master
    int b0 = blockIdx.x * 16;
    int tid = threadIdx.x;
    int w = tid >> 6, lane = tid & 63;
    int fr = lane & 15, hi = lane >> 4;

    // one-time: W_hh fp32 -> bf16 swizzled LDS
    for (int idx = tid; idx < 1536; idx += 256) {
        int row = idx >> 3, slot = idx & 7;
        const float* src = w_hh + row * 64 + slot * 8;
        short8 o;
#pragma unroll
        for (int q = 0; q < 8; ++q) o[q] = (short)f2b(src[q]);
        *(short8*)&wl[row * 64 + ((slot ^ (row & 7)) << 3)] = o;
    }
    for (int idx = tid; idx < 1024; idx += 256) {
        hf[idx] = 0.f;
        hb[0][idx] = 0;
    }

    int c = w * 16 + fr;                 // gate col / h index owned by this lane
    float br_ = b_hh[c], bz_ = b_hh[64 + c], bn_ = b_hh[128 + c];
    int g0 = c, g1 = 64 + c, g2 = 128 + c;   // W rows (frag rows); g&7 == fr&7 for all

    const float* xwb = xw + (size_t)b0 * SS * 192;
    size_t xrow[4];
#pragma unroll
    for (int j = 0; j < 4; ++j) xrow[j] = (size_t)(hi * 4 + j) * SS * 192;

    float xr[4], xz[4], xn[4];
#pragma unroll
    for (int j = 0; j < 4; ++j) {
        const float* p = xwb + xrow[j];
        xr[j] = p[c]; xz[j] = p[64 + c]; xn[j] = p[128 + c];
    }
    __syncthreads();

    int cur = 0;
    for (int t = 0; t < SS; ++t) {
        int tn = (t + 1 < SS) ? t + 1 : t;
        float pxr[4], pxz[4], pxn[4];
#pragma unroll
        for (int j = 0; j < 4; ++j) {                 // prefetch next step's xw
            const float* p = xwb + xrow[j] + (size_t)tn * 192;
            pxr[j] = p[c]; pxz[j] = p[64 + c]; pxn[j] = p[128 + c];
        }
        f32x4 ar = {br_, br_, br_, br_};              // bias as C-in
        f32x4 az = {bz_, bz_, bz_, bz_};
        f32x4 an = {bn_, bn_, bn_, bn_};
#pragma unroll
        for (int ks = 0; ks < 2; ++ks) {
            int soff = (((ks << 2) + hi) ^ (fr & 7)) << 3;
            short8 af  = *(const short8*)&hb[cur][fr * 64 + soff];
            short8 wfr = *(const short8*)&wl[g0 * 64 + soff];
            short8 wfz = *(const short8*)&wl[g1 * 64 + soff];
            short8 wfn = *(const short8*)&wl[g2 * 64 + soff];
            ar = __builtin_amdgcn_mfma_f32_16x16x32_bf16(af, wfr, ar, 0, 0, 0);
            az = __builtin_amdgcn_mfma_f32_16x16x32_bf16(af, wfz, az, 0, 0, 0);
            an = __builtin_amdgcn_mfma_f32_16x16x32_bf16(af, wfn, an, 0, 0, 0);
        }
#pragma unroll
        for (int j = 0; j < 4; ++j) {
            int rb = hi * 4 + j;
            float hold = hf[rb * 64 + c];             // exclusive owner, no race
            float r  = 1.f / (1.f + __expf(-(xr[j] + ar[j])));
            float zg = 1.f / (1.f + __expf(-(xz[j] + az[j])));
            float nx = xn[j] + r * an[j];
            float n  = 2.f / (1.f + __expf(-2.f * nx)) - 1.f;   // tanh
            float hn = (1.f - zg) * n + zg * hold;
            hf[rb * 64 + c] = hn;
            u16 hv = f2b(hn);
            hb[cur ^ 1][rb * 64 + (((c >> 3) ^ (rb & 7)) << 3) + (c & 7)] = hv;
            hsb[((size_t)(b0 + rb) * SS + t) * 64 + c] = hv;
        }
        __syncthreads();                              // hb[cur^1] complete before next reads
        cur ^= 1;
#pragma unroll
        for (int j = 0; j < 4; ++j) { xr[j] = pxr[j]; xz[j] = pxz[j]; xn[j] = pxn[j]; }
    }
}

// ---------------------------------------------------------------- bf16 MFMA GEMM (BK=64, swizzled)
// MODE: 1=f32 C, 2=bf16 Cb, 3=both, 4=fused residual+LayerNorm (N==128, bn==0)
__device__ __forceinline__ void gl_lds16(const void* g, void* s) {
    __builtin_amdgcn_global_load_lds(
        (const __attribute__((address_space(1))) void*)g,
        (__attribute__((address_space(3))) void*)s, 16, 0, 0);
}

template <int MODE, bool RELU>
__global__ __launch_bounds__(256, 2) void mfma_gemm(const u16* __restrict__ A,
                                                    const u16* __restrict__ W,
                                                    const float* __restrict__ bias,
                                                    float* __restrict__ C,
                                                    u16* __restrict__ Cb,
                                                    const float* __restrict__ lns,
                                                    const float* __restrict__ lnb,
                                                    int M, int N, int K) {
    __shared__ __align__(16) u16 Al[128 * 64];
    __shared__ __align__(16) u16 Bl[128 * 64];
    __shared__ float lred[2][2][128];
    int bm = blockIdx.x, bn = blockIdx.y;
    int tid = threadIdx.x;
    int w = tid >> 6, lane = tid & 63;
    int wrow = (w >> 1) * 64, wcol = (w & 1) * 64;
    int fr = lane & 15, hi = lane >> 4;
    int rl = lane >> 3;
    int sl = lane & 7;
    int ssl = sl ^ rl;

    const u16* Ag = A + ((size_t)bm * 128) * K + ssl * 8;
    const u16* Wg = W + ((size_t)bn * 128) * K + ssl * 8;

    f32x4 acc[4][4];
#pragma unroll
    for (int i = 0; i < 4; ++i)
#pragma unroll
        for (int jj = 0; jj < 4; ++jj) acc[i][jj] = (f32x4){0.f, 0.f, 0.f, 0.f};

    int ar[4], br[4];
#pragma unroll
    for (int m = 0; m < 4; ++m) {
        ar[m] = (wrow + m * 16 + fr) * 64;
        br[m] = (wcol + m * 16 + fr) * 64;
    }
    int swz = (fr & 7);

    for (int kt = 0; kt < K; kt += 64) {
        __syncthreads();
#pragma unroll
        for (int i = 0; i < 4; ++i) {
            int c = w * 4 + i;
            int row = c * 8 + rl;
            gl_lds16(Ag + (size_t)row * K + kt, &Al[c * 512]);
            gl_lds16(Wg + (size_t)row * K + kt, &Bl[c * 512]);
        }
        __syncthreads();
#pragma unroll
        for (int kk = 0; kk < 2; ++kk) {
            short8 a[4], bq[4];
            int soff = (((kk << 2) + hi) ^ swz) << 3;
#pragma unroll
            for (int m = 0; m < 4; ++m)
                a[m] = *(const short8*)&Al[ar[m] + soff];
#pragma unroll
            for (int n = 0; n < 4; ++n)
                bq[n] = *(const short8*)&Bl[br[n] + soff];
#pragma unroll
            for (int m = 0; m < 4; ++m)
#pragma unroll
                for (int n = 0; n < 4; ++n)
                    acc[m][n] = __builtin_amdgcn_mfma_f32_16x16x32_bf16(a[m], bq[n], acc[m][n], 0, 0, 0);
        }
    }

    float bv[4];
#pragma unroll
    for (int n = 0; n < 4; ++n) bv[n] = bias[bn * 128 + wcol + n * 16 + fr];

    if (MODE == 4) {
        float v[4][4][4];
#pragma unroll
        for (int m = 0; m < 4; ++m)
#pragma unroll
            for (int j = 0; j < 4; ++j) {
                int row = bm * 128 + wrow + m * 16 + hi * 4 + j;
#pragma unroll
                for (int n = 0; n < 4; ++n)
                    v[m][n][j] = acc[m][n][j] + bv[n] + C[(size_t)row * 128 + wcol + n * 16 + fr];
            }
#pragma unroll
        for (int m = 0; m < 4; ++m)
#pragma unroll
            for (int j = 0; j < 4; ++j) {
                float s = v[m][0][j] + v[m][1][j] + v[m][2][j] + v[m][3][j];
                float q = v[m][0][j]*v[m][0][j] + v[m][1][j]*v[m][1][j]
                        + v[m][2][j]*v[m][2][j] + v[m][3][j]*v[m][3][j];
#pragma unroll
                for (int off = 1; off <= 8; off <<= 1) {
                    s += __shfl_xor(s, off);
                    q += __shfl_xor(q, off);
                }
                if (fr == 0) {
                    int lrow = wrow + m * 16 + hi * 4 + j;
                    lred[0][w & 1][lrow] = s;
                    lred[1][w & 1][lrow] = q;
                }
            }
        __syncthreads();
        float sv[4], bb[4];
#pragma unroll
        for (int n = 0; n < 4; ++n) {
            sv[n] = lns[wcol + n * 16 + fr];
            bb[n] = lnb[wcol + n * 16 + fr];
        }
#pragma unroll
        for (int m = 0; m < 4; ++m)
#pragma unroll
            for (int j = 0; j < 4; ++j) {
                int lrow = wrow + m * 16 + hi * 4 + j;
                float mean = (lred[0][0][lrow] + lred[0][1][lrow]) * (1.f / 128.f);
                float msq  = (lred[1][0][lrow] + lred[1][1][lrow]) * (1.f / 128.f);
                float rstd = rsqrtf(msq - mean * mean + 1e-5f);
                int row = bm * 128 + lrow;
#pragma unroll
                for (int n = 0; n < 4; ++n) {
                    int col = wcol + n * 16 + fr;
                    float o = (v[m][n][j] - mean) * rstd * sv[n] + bb[n];
                    C[(size_t)row * 128 + col] = o;
                    Cb[(size_t)row * 128 + col] = f2b(o);
                }
            }
    } else {
#pragma unroll
        for (int m = 0; m < 4; ++m) {
#pragma unroll
            for (int j = 0; j < 4; ++j) {
                int row = bm * 128 + wrow + m * 16 + hi * 4 + j;
#pragma unroll
                for (int n = 0; n < 4; ++n) {
                    int col = bn * 128 + wcol + n * 16 + fr;
                    float vv = acc[m][n][j] + bv[n];
                    if (RELU) vv = fmaxf(vv, 0.f);
                    if (MODE & 1) C[(size_t)row * N + col] = vv;
                    if (MODE & 2) Cb[(size_t)row * N + col] = f2b(vv);
                }
            }
        }
    }
}

// ---------------------------------------------------------------- fused FF: relu(zb@W1^T+b1)@W2^T+b2
// + residual + LN2, one block per 128 rows (grid 256 = 1 block/CU), no global ff buffer.
// GEMM1 computed transposed (C1[ff, r]) so a1 writes pack 4 ff-cols per b64; GEMM2 computes
// out^T (C2[o, r]) and epilogue LN reduces over o (lane-local 16 + shfl over hi + 2-wave LDS).
__global__ __launch_bounds__(256, 1) void ff_fused_kernel(const u16* __restrict__ zbin,
                                                          const u16* __restrict__ w1,
                                                          const float* __restrict__ b1,
                                                          const u16* __restrict__ w2,
                                                          const float* __restrict__ b2,
                                                          const float* __restrict__ lns,
                                                          const float* __restrict__ lnb,
                                                          float* __restrict__ z,
                                                          u16* __restrict__ zbout) {
    __shared__ __align__(16) u16 ZB[2][128 * 64];
    __shared__ __align__(16) u16 W1C[2][128 * 64];
    __shared__ __align__(16) u16 W2C[2][128 * 64];
    __shared__ __align__(16) u16 A1[2][128 * 64];
    __shared__ float lred[2][2][128];
    int bm = blockIdx.x;
    int tid = threadIdx.x;
    int w = tid >> 6, lane = tid & 63;
    int wrow = (w >> 1) * 64, wcol = (w & 1) * 64;
    int fr = lane & 15, hi = lane >> 4;
    int rl = lane >> 3, ssl = (lane & 7) ^ rl;
    int swz = fr & 7;
    int xh = wrow >> 6;            // this wave's x-half (ff / o)

    // stage ZB once (rows = batch)
#pragma unroll
    for (int hk = 0; hk < 2; ++hk)
#pragma unroll
        for (int i = 0; i < 4; ++i) {
            int ch = w * 4 + i, row = ch * 8 + rl;
            gl_lds16(zbin + ((size_t)(bm * 128 + row)) * 128 + hk * 64 + ssl * 8, &ZB[hk][ch * 512]);
        }

    f32x4 acc2[4][4];
#pragma unroll
    for (int m = 0; m < 4; ++m)
#pragma unroll
        for (int n = 0; n < 4; ++n) acc2[m][n] = (f32x4){0.f, 0.f, 0.f, 0.f};

    for (int ci = 0; ci < 16; ++ci) {
        // stage W1 chunk [128 ff][128 k] and W2 slice [128 o][128 ff]
#pragma unroll
        for (int hk = 0; hk < 2; ++hk)
#pragma unroll
            for (int i = 0; i < 4; ++i) {
                int ch = w * 4 + i, row = ch * 8 + rl;
                gl_lds16(w1 + ((size_t)(ci * 128 + row)) * 128 + hk * 64 + ssl * 8, &W1C[hk][ch * 512]);
                gl_lds16(w2 + ((size_t)row) * 2048 + ci * 128 + hk * 64 + ssl * 8, &W2C[hk][ch * 512]);
            }
        __syncthreads();   // staging done (vmcnt0) + prior GEMM2 A1/W2C reads done

        // GEMM1: C1[x=ff, y=r] = W1C x ZB
        f32x4 acc1[4][4];
#pragma unroll
        for (int m = 0; m < 4; ++m)
#pragma unroll
            for (int n = 0; n < 4; ++n) acc1[m][n] = (f32x4){0.f, 0.f, 0.f, 0.f};
#pragma unroll
        for (int ks = 0; ks < 4; ++ks) {
            int hk = ks >> 1;
            int soff = ((((ks & 1) << 2) + hi) ^ swz) << 3;
            short8 a[4], b[4];
#pragma unroll
            for (int m = 0; m < 4; ++m)
                a[m] = *(const short8*)&W1C[hk][(wrow + m * 16 + fr) * 64 + soff];
#pragma unroll
            for (int n = 0; n < 4; ++n)
                b[n] = *(const short8*)&ZB[hk][(wcol + n * 16 + fr) * 64 + soff];
#pragma unroll
            for (int m = 0; m < 4; ++m)
#pragma unroll
                for (int n = 0; n < 4; ++n)
                    acc1[m][n] = __builtin_amdgcn_mfma_f32_16x16x32_bf16(a[m], b[n], acc1[m][n], 0, 0, 0);
        }
        // bias + relu -> bf16, write a1[r][ff] (b64 per j-quad, swizzled on r)
#pragma unroll
        for (int m = 0; m < 4; ++m) {
            int x0 = wrow + m * 16 + hi * 4;        // ff base, 4 consecutive (j)
            float4 bb = *(const float4*)&b1[ci * 128 + x0];
            int slot = (x0 & 63) >> 3;
            int wadd = x0 & 7;
#pragma unroll
            for (int n = 0; n < 4; ++n) {
                int r = wcol + n * 16 + fr;
                float v0 = fmaxf(acc1[m][n][0] + bb.x, 0.f);
                float v1 = fmaxf(acc1[m][n][1] + bb.y, 0.f);
                float v2 = fmaxf(acc1[m][n][2] + bb.z, 0.f);
                float v3 = fmaxf(acc1[m][n][3] + bb.w, 0.f);
                uint2 pk;
                pk.x = (unsigned)f2b(v0) | ((unsigned)f2b(v1) << 16);
                pk.y = (unsigned)f2b(v2) | ((unsigned)f2b(v3) << 16);
                *(uint2*)&A1[xh][r * 64 + ((slot ^ (r & 7)) << 3) + wadd] = pk;
            }
        }
        __syncthreads();   // A1 ready

        // GEMM2: C2[x=o, y=r] += W2C x A1
#pragma unroll
        for (int ks = 0; ks < 4; ++ks) {
            int hk = ks >> 1;
            int soff = ((((ks & 1) << 2) + hi) ^ swz) << 3;
            short8 a[4], b[4];
#pragma unroll
            for (int m = 0; m < 4; ++m)
                a[m] = *(const short8*)&W2C[hk][(wrow + m * 16 + fr) * 64 + soff];
#pragma unroll
            for (int n = 0; n < 4; ++n)
                b[n] = *(const short8*)&A1[hk][(wcol + n * 16 + fr) * 64 + soff];
#pragma unroll
            for (int m = 0; m < 4; ++m)
#pragma unroll
                for (int n = 0; n < 4; ++n)
                    acc2[m][n] = __builtin_amdgcn_mfma_f32_16x16x32_bf16(a[m], b[n], acc2[m][n], 0, 0, 0);
        }
        __syncthreads();   // W2C/A1 reads done before next chunk's staging
    }

    // epilogue: v = acc2 + b2[x] + z_old[y][x]; LN over x(=o, 128) per row y; write z, zb
    float vv[4][4][4];
#pragma unroll
    for (int m = 0; m < 4; ++m) {
        int x0 = wrow + m * 16 + hi * 4;
        float4 bb = *(const float4*)&b2[x0];
#pragma unroll
        for (int n = 0; n < 4; ++n) {
            int y = wcol + n * 16 + fr;
            float4 zo = *(const float4*)&z[((size_t)(bm * 128 + y)) * 128 + x0];
            vv[m][n][0] = acc2[m][n][0] + bb.x + zo.x;
            vv[m][n][1] = acc2[m][n][1] + bb.y + zo.y;
            vv[m][n][2] = acc2[m][n][2] + bb.z + zo.z;
            vv[m][n][3] = acc2[m][n][3] + bb.w + zo.w;
        }
    }
#pragma unroll
    for (int n = 0; n < 4; ++n) {
        float s = 0.f, q = 0.f;
#pragma unroll
        for (int m = 0; m < 4; ++m)
#pragma unroll
            for (int j = 0; j < 4; ++j) { float v = vv[m][n][j]; s += v; q += v * v; }
        s += __shfl_xor(s, 16); s += __shfl_xor(s, 32);
        q += __shfl_xor(q, 16); q += __shfl_xor(q, 32);
        if (hi == 0) {
            int y = wcol + n * 16 + fr;
            lred[0][xh][y] = s;
            lred[1][xh][y] = q;
        }
    }
    __syncthreads();
#pragma unroll
    for (int n = 0; n < 4; ++n) {
        int y = wcol + n * 16 + fr;
        float mean = (lred[0][0][y] + lred[0][1][y]) * (1.f / 128.f);
        float msq  = (lred[1][0][y] + lred[1][1][y]) * (1.f / 128.f);
        float rstd = rsqrtf(msq - mean * mean + 1e-5f);
#pragma unroll
        for (int m = 0; m < 4; ++m) {
            int x0 = wrow + m * 16 + hi * 4;
            float4 sv = *(const float4*)&lns[x0];
            float4 bv = *(const float4*)&lnb[x0];
            float o0 = (vv[m][n][0] - mean) * rstd * sv.x + bv.x;
            float o1 = (vv[m][n][1] - mean) * rstd * sv.y + bv.y;
            float o2 = (vv[m][n][2] - mean) * rstd * sv.z + bv.z;
            float o3 = (vv[m][n][3] - mean) * rstd * sv.w + bv.w;
            size_t zoff = ((size_t)(bm * 128 + y)) * 128 + x0;
            *(float4*)&z[zoff] = (float4){o0, o1, o2, o3};
            uint2 pk;
            pk.x = (unsigned)f2b(o0) | ((unsigned)f2b(o1) << 16);
            pk.y = (unsigned)f2b(o2) | ((unsigned)f2b(o3) << 16);
            *(uint2*)&zbout[zoff] = pk;
        }
    }
}

// ---------------------------------------------------------------- attention (bf16 qkv in, bf16 out)
__global__ __launch_bounds__(256) void attn_kernel(const u16* __restrict__ qkv,
                                                   const float* __restrict__ tm,
                                                   u16* __restrict__ attno) {
    int bh = blockIdx.x;
    int b = bh / NHH, hd = bh % NHH;
    int s = threadIdx.x;

    __shared__ float Kt[64][32];
    __shared__ float Vt[64][32];
    __shared__ float tms[64];

    float q[32];
    const u16* qrow = qkv + ((size_t)b * SS + s) * 384 + hd * 32;
#pragma unroll
    for (int j = 0; j < 32; j += 8) {
        short8 v = *(const short8*)&qrow[j];
#pragma unroll
        for (int jj = 0; jj < 8; ++jj) q[j + jj] = b2f((u16)v[jj]);
    }
    const float scale = 0.17677669529663687f;
    float denom = 0.f;
    float o[32];
#pragma unroll
    for (int j = 0; j < 32; ++j) o[j] = 0.f;

    for (int kt = 0; kt < SS; kt += 64) {
        __syncthreads();
        {
            int r = s >> 2, c = (s & 3) * 8;
            const u16* kb = qkv + ((size_t)b * SS + kt + r) * 384 + 128 + hd * 32 + c;
            const u16* vb = qkv + ((size_t)b * SS + kt + r) * 384 + 256 + hd * 32 + c;
            short8 kv = *(const short8*)kb;
            short8 vvv = *(const short8*)vb;
#pragma unroll
            for (int jj = 0; jj < 8; ++jj) {
                Kt[r][c + jj] = b2f((u16)kv[jj]);
                Vt[r][c + jj] = b2f((u16)vvv[jj]);
            }
        }
        if (s < 64) tms[s] = tm[b * SS + kt + s];
        __syncthreads();
        for (int k = 0; k < 64; ++k) {
            float acc = 0.f;
#pragma unroll
            for (int j = 0; j < 32; ++j) acc += q[j] * Kt[k][j];
            float sc = acc * scale + (tms[k] > 0.f ? 0.f : NEGV);
            float e = __expf(sc);
            denom += e;
#pragma unroll
            for (int j = 0; j < 32; ++j) o[j] += e * Vt[k][j];
        }
    }
    float inv = 1.f / denom;
    u16* orow = attno + ((size_t)b * SS + s) * DD + hd * 32;
#pragma unroll
    for (int j = 0; j < 32; j += 8) {
        short8 ov;
#pragma unroll
        for (int jj = 0; jj < 8; ++jj) ov[jj] = (short)f2b(o[j + jj] * inv);
        *(short8*)&orow[j] = ov;
    }
}

// ---------------------------------------------------------------- score = z @ score_w^T + b (masked)
__global__ __launch_bounds__(256) void score_kernel(const float* __restrict__ z,
                                                    const float* __restrict__ score_w,
                                                    const float* __restrict__ score_b,
                                                    const float* __restrict__ tm,
                                                    float* __restrict__ scores) {
    int row = blockIdx.x * 64 + (threadIdx.x >> 2);
    int c = threadIdx.x & 3;
    const float* zr = z + (size_t)row * DD + c * 32;
    const float* wr = score_w + c * 32;
    float acc = 0.f;
#pragma unroll
    for (int j = 0; j < 32; j += 4) {
        float4 a = *(const float4*)(zr + j), w = *(const float4*)(wr + j);
        acc += a.x * w.x + a.y * w.y + a.z * w.z + a.w * w.w;
    }
    acc += __shfl_xor(acc, 1);
    acc += __shfl_xor(acc, 2);
    if (c == 0) {
        float sc = acc + score_b[0];
        scores[row] = (tm[row] > 0.f) ? sc : NEGV;
    }
}

// ---------------------------------------------------------------- softmax over S + weighted pool
__global__ __launch_bounds__(256) void pool_kernel(const float* __restrict__ z,
                                                   const float* __restrict__ scores,
                                                   float* __restrict__ pooled) {
    int b = blockIdx.x;
    int tid = threadIdx.x;
    __shared__ float al[SS];
    __shared__ float red[8];
    __shared__ float pp[2][128];

    float sc = scores[b * SS + tid];
    float m = sc;
#pragma unroll
    for (int off = 32; off; off >>= 1) m = fmaxf(m, __shfl_xor(m, off));
    if ((tid & 63) == 0) red[tid >> 6] = m;
    __syncthreads();
    m = fmaxf(fmaxf(red[0], red[1]), fmaxf(red[2], red[3]));
    float e = __expf(sc - m);
    float ssum = e;
#pragma unroll
    for (int off = 32; off; off >>= 1) ssum += __shfl_xor(ssum, off);
    if ((tid & 63) == 0) red[4 + (tid >> 6)] = ssum;
    __syncthreads();
    ssum = red[4] + red[5] + red[6] + red[7];
    al[tid] = e / ssum;
    __syncthreads();

    int d = tid & 127, half = tid >> 7;
    float acc = 0.f;
    for (int t = half; t < SS; t += 2) acc += al[t] * z[((size_t)b * SS + t) * DD + d];
    pp[half][d] = acc;
    __syncthreads();
    if (tid < 128) pooled[b * 128 + tid] = pp[0][tid] + pp[1][tid];
}

// ---------------------------------------------------------------- routed heads
__global__ __launch_bounds__(128) void head_kernel(const float* __restrict__ pooled,
                                                   const float* __restrict__ reg_w,
                                                   const float* __restrict__ reg_b,
                                                   const float* __restrict__ bin_w,
                                                   const float* __restrict__ bin_b,
                                                   const int* __restrict__ wid,
                                                   float* __restrict__ out) {
    int b = blockIdx.x, tid = threadIdx.x;
    __shared__ float p[128];
    p[tid] = pooled[b * 128 + tid];
    __syncthreads();
    if (tid < 9) {
        int w = wid[b];
        const float* wrow;
        float bias;
        if (tid < 8) { wrow = reg_w + ((size_t)w * 8 + tid) * 128; bias = reg_b[w * 8 + tid]; }
        else         { wrow = bin_w + (size_t)w * 128;             bias = bin_b[w]; }
        float acc = bias;
        for (int k = 0; k < 128; ++k) acc += wrow[k] * p[k];
        if (tid < 8) out[b * 8 + tid] = acc;
        else         out[1024 + b] = acc;
    }
}

// ================================================================ host
extern "C" void kernel_launch(void* const* d_in, const int* in_sizes, int n_in,
                              void* d_out, int out_size, void* d_ws, size_t ws_size,
                              hipStream_t stream) {
    const float* x         = (const float*)d_in[0];
    const float* mask      = (const float*)d_in[1];
    const float* delta     = (const float*)d_in[2];
    const float* gru_w_ih  = (const float*)d_in[3];
    const float* gru_w_hh  = (const float*)d_in[4];
    const float* gru_b_ih  = (const float*)d_in[5];
    const float* gru_b_hh  = (const float*)d_in[6];
    const float* dm_w      = (const float*)d_in[7];
    const float* dm_b      = (const float*)d_in[8];
    const float* in_proj_w = (const float*)d_in[9];
    const float* in_proj_b = (const float*)d_in[10];
    const float* out_proj_w= (const float*)d_in[11];
    const float* out_proj_b= (const float*)d_in[12];
    const float* lin1_w    = (const float*)d_in[13];
    const float* lin1_b    = (const float*)d_in[14];
    const float* lin2_w    = (const float*)d_in[15];
    const float* lin2_b    = (const float*)d_in[16];
    const float* ln1_s     = (const float*)d_in[17];
    const float* ln1_bb    = (const float*)d_in[18];
    const float* ln2_s     = (const float*)d_in[19];
    const float* ln2_bb    = (const float*)d_in[20];
    const float* score_w   = (const float*)d_in[21];
    const float* score_b   = (const float*)d_in[22];
    const float* reg_w     = (const float*)d_in[23];
    const float* reg_b     = (const float*)d_in[24];
    const float* bin_w     = (const float*)d_in[25];
    const float* bin_b     = (const float*)d_in[26];
    const int*   window_id = (const int*)d_in[27];
    float* out = (float*)d_out;

    char* w8 = (char*)d_ws;
    float* z      = (float*)(w8 + 0);            // 16,777,216
    u16*   zb     = (u16*)  (w8 + 16777216);     //  8,388,608
    u16*   hsb    = (u16*)  (w8 + 25165824);     //  4,194,304
    u16*   wb_dm  = (u16*)  (w8 + 29360128);     //     16,384
    u16*   wb_ip  = (u16*)  (w8 + 29376512);     //    196,608
    u16*   wb_op  = (u16*)  (w8 + 29573120);     //     65,536
    u16*   wb_l1  = (u16*)  (w8 + 29638656);     //  1,048,576
    u16*   wb_l2  = (u16*)  (w8 + 30687232);     //  1,048,576
    float* tm     = (float*)(w8 + 31735808);     //    131,072
    float* scores = (float*)(w8 + 31866880);     //    131,072
    float* pooled = (float*)(w8 + 31997952);     //     65,536
    float* xw     = (float*)(w8 + 32063488);     // 25,165,824 (GRU: xw fp32 | later: qkvb bf16)
    u16*   qkvb   = (u16*)  (w8 + 32063488);
    u16*   attnob = (u16*)  (w8 + 57229312);     //  8,388,608   (total ~65.6MB)

    cvt_all_kernel<<<580, 256, 0, stream>>>(dm_w, in_proj_w, out_proj_w, lin1_w, lin2_w,
                                            wb_dm, wb_ip, wb_op, wb_l1, wb_l2);

    tm_kernel<<<(BB * SS + 255) / 256, 256, 0, stream>>>(mask, tm);
    xw_kernel<<<BB * SS / XW_RPB, 192, 0, stream>>>(x, mask, delta, gru_w_ih, gru_b_ih, xw);
    gru_scan_kernel<<<8, 256, 0, stream>>>(gru_w_hh, gru_b_hh, xw, hsb);

    mfma_gemm<3, false><<<dim3(256, 1), 256, 0, stream>>>(
        hsb, wb_dm, dm_b, z, zb, nullptr, nullptr, 32768, 128, 64);

    for (int l = 0; l < LL; ++l) {
        mfma_gemm<2, false><<<dim3(256, 3), 256, 0, stream>>>(
            zb, wb_ip + (size_t)l * 49152, in_proj_b + l * 384, nullptr, qkvb,
            nullptr, nullptr, 32768, 384, 128);
        attn_kernel<<<BB * NHH, 256, 0, stream>>>(qkvb, tm, attnob);
        // out_proj + residual + LN1 fused
        mfma_gemm<4, false><<<dim3(256, 1), 256, 0, stream>>>(
            attnob, wb_op + (size_t)l * 16384, out_proj_b + l * 128, z, zb,
            ln1_s + l * 128, ln1_bb + l * 128, 32768, 128, 128);
        // fused FF (lin1+relu+lin2+residual+LN2), 1 dispatch, 256 blocks
        ff_fused_kernel<<<256, 256, 0, stream>>>(
            zb, wb_l1 + (size_t)l * 262144, lin1_b + l * 2048,
            wb_l2 + (size_t)l * 262144, lin2_b + l * 128,
            ln2_s + l * 128, ln2_bb + l * 128, z, zb);
    }

    score_kernel<<<BB * SS / 64, 256, 0, stream>>>(z, score_w, score_b, tm, scores);
    pool_kernel<<<BB, 256, 0, stream>>>(z, scores, pooled);
    head_kernel<<<BB, 128, 0, stream>>>(pooled, reg_w, reg_b, bin_w, bin_b, window_id, out);
}

// Round 9
// 680.832 us; speedup vs baseline: 1.0903x; 1.0211x over previous
//
#include <hip/hip_runtime.h>

typedef __attribute__((ext_vector_type(8))) short short8;
typedef __attribute__((ext_vector_type(4))) float f32x4;
typedef unsigned short u16;

#define BB   128
#define SS   256
#define FIN  40
#define HH   64
#define DD   128
#define NHH  4
#define LL   2
#define NEGV (-1e9f)

__device__ __forceinline__ u16 f2b(float f) {
    unsigned u = __float_as_uint(f);
    return (u16)((u + 0x7FFFu + ((u >> 16) & 1u)) >> 16);
}
__device__ __forceinline__ float b2f(u16 u) {
    return __uint_as_float(((unsigned)u) << 16);
}

// ---------------------------------------------------------------- merged fp32 -> bf16 weight convert
__global__ __launch_bounds__(256) void cvt_all_kernel(const float* __restrict__ dm_w,
                                                      const float* __restrict__ ip_w,
                                                      const float* __restrict__ op_w,
                                                      const float* __restrict__ l1_w,
                                                      const float* __restrict__ l2_w,
                                                      u16* __restrict__ o_dm, u16* __restrict__ o_ip,
                                                      u16* __restrict__ o_op, u16* __restrict__ o_l1,
                                                      u16* __restrict__ o_l2) {
    int blk = blockIdx.x;
    const float* s; u16* d; int off;
    if      (blk < 4)   { s = dm_w; d = o_dm; off = blk; }
    else if (blk < 52)  { s = ip_w; d = o_ip; off = blk - 4; }
    else if (blk < 68)  { s = op_w; d = o_op; off = blk - 52; }
    else if (blk < 324) { s = l1_w; d = o_l1; off = blk - 68; }
    else                { s = l2_w; d = o_l2; off = blk - 324; }
    int i = (off * 256 + threadIdx.x) * 8;
    float4 a = *(const float4*)&s[i];
    float4 b = *(const float4*)&s[i + 4];
    short8 o;
    o[0] = (short)f2b(a.x); o[1] = (short)f2b(a.y); o[2] = (short)f2b(a.z); o[3] = (short)f2b(a.w);
    o[4] = (short)f2b(b.x); o[5] = (short)f2b(b.y); o[6] = (short)f2b(b.z); o[7] = (short)f2b(b.w);
    *(short8*)&d[i] = o;
}

// ---------------------------------------------------------------- time mask
__global__ __launch_bounds__(256) void tm_kernel(const float* __restrict__ mask,
                                                 float* __restrict__ tm) {
    int i = blockIdx.x * blockDim.x + threadIdx.x;
    if (i >= BB * SS) return;
    const float* m = mask + (size_t)i * FIN;
    float s = 0.f;
    for (int f = 0; f < FIN; ++f) s += m[f];
    tm[i] = (s > 0.f) ? 1.f : 0.f;
}

// ------------------------------------------------- xwt = concat(x,mask,delta) @ W_ih^T + b_ih
// TRANSPOSED output layout for the GRU: xwt[group 0..7][t 0..255][gatecol 0..191][rb 0..15]
// block = (group, t); thread tid = gatecol; writes 16 consecutive floats (coalesced float4 x4).
__global__ __launch_bounds__(192) void xw_kernel(const float* __restrict__ x,
                                                 const float* __restrict__ mask,
                                                 const float* __restrict__ delta,
                                                 const float* __restrict__ w_ih,
                                                 const float* __restrict__ b_ih,
                                                 float* __restrict__ xwt) {
    __shared__ float inp[16][120];
    __shared__ float wl[192][21];
    int group = blockIdx.x >> 8;
    int t = blockIdx.x & 255;
    int tid = threadIdx.x;

    for (int idx = tid; idx < 16 * 120; idx += 192) {
        int r = idx / 120, k = idx % 120;
        size_t g = (size_t)(group * 16 + r) * 256 + t;
        float v;
        if (k < 40)      v = x[g * FIN + k];
        else if (k < 80) v = mask[g * FIN + (k - 40)];
        else             v = delta[g * FIN + (k - 80)];
        inp[r][k] = v;
    }

    float acc[16];
#pragma unroll
    for (int r = 0; r < 16; ++r) acc[r] = 0.f;

    for (int kt = 0; kt < 6; ++kt) {
        __syncthreads();
        for (int idx = tid; idx < 192 * 20; idx += 192) {
            int r = idx / 20, k = idx % 20;
            wl[r][k] = w_ih[(size_t)r * 120 + kt * 20 + k];
        }
        __syncthreads();
#pragma unroll
        for (int kk = 0; kk < 20; ++kk) {
            float w = wl[tid][kk];
            int kg = kt * 20 + kk;
#pragma unroll
            for (int r = 0; r < 16; ++r) acc[r] += w * inp[r][kg];
        }
    }
    float bias = b_ih[tid];
    float* o = xwt + ((size_t)(group * 256 + t) * 192 + tid) * 16;
#pragma unroll
    for (int r = 0; r < 16; r += 4) {
        float4 v = {acc[r] + bias, acc[r + 1] + bias, acc[r + 2] + bias, acc[r + 3] + bias};
        *(float4*)&o[r] = v;
    }
}

// ---------------------------------------------------------------- MFMA GRU scan v3
// 8 blocks x 16 batch rows, 4 waves. Fixes R8's 2060cyc/step:
// (1) raw s_barrier + lgkmcnt(0) only (NOT __syncthreads' vmcnt(0) drain) -> xw prefetch
//     loads stay in flight across the barrier (T4/AITER pattern);
// (2) depth-2 prefetch from TRANSPOSED xwt: 3 float4 loads/step, 2-step latency cover;
// (3) h state in registers (lane exclusively owns rows hi*4..+3 at col c) - no hf LDS.
__device__ __forceinline__ float gru_gate(float xr, float xz, float xn,
                                          float ar, float az, float an, float hold) {
    float r  = 1.f / (1.f + __expf(-(xr + ar)));
    float zg = 1.f / (1.f + __expf(-(xz + az)));
    float nx = xn + r * an;
    float n  = 2.f / (1.f + __expf(-2.f * nx)) - 1.f;   // tanh
    return (1.f - zg) * n + zg * hold;
}

__global__ __launch_bounds__(256, 1) void gru_scan_kernel(const float* __restrict__ w_hh,
                                                          const float* __restrict__ b_hh,
                                                          const float* __restrict__ xwt,
                                                          u16* __restrict__ hsb) {
    __shared__ __align__(16) u16 wl[192 * 64];     // bf16 W_hh, slot^(row&7) swizzled (24KB)
    __shared__ __align__(16) u16 hb[2][16 * 64];   // bf16 h A-frag source, same swizzle
    int b0 = blockIdx.x * 16;
    int tid = threadIdx.x;
    int w = tid >> 6, lane = tid & 63;
    int fr = lane & 15, hi = lane >> 4;

    // one-time: W_hh fp32 -> bf16 swizzled LDS
    for (int idx = tid; idx < 1536; idx += 256) {
        int row = idx >> 3, slot = idx & 7;
        const float* src = w_hh + row * 64 + slot * 8;
        short8 o;
#pragma unroll
        for (int q = 0; q < 8; ++q) o[q] = (short)f2b(src[q]);
        *(short8*)&wl[row * 64 + ((slot ^ (row & 7)) << 3)] = o;
    }
    for (int idx = tid; idx < 1024; idx += 256) hb[0][idx] = 0;

    int c = w * 16 + fr;                 // gate col / h col owned by this lane
    float br_ = b_hh[c], bz_ = b_hh[64 + c], bn_ = b_hh[128 + c];
    int g0 = c, g1 = 64 + c, g2 = 128 + c;

    const float* xg = xwt + (size_t)blockIdx.x * (256 * 192 * 16);
    int lo = hi * 4;                     // row sub-offset inside the 16-float rb vector

    // h state in registers (exclusive per lane)
    float hr0 = 0.f, hr1 = 0.f, hr2 = 0.f, hr3 = 0.f;

    // hb write offsets (u16 units), rb = lo+j
    int wo0 = (lo + 0) * 64 + ((((c >> 3) ^ ((lo + 0) & 7))) << 3) + (c & 7);
    int wo1 = (lo + 1) * 64 + ((((c >> 3) ^ ((lo + 1) & 7))) << 3) + (c & 7);
    int wo2 = (lo + 2) * 64 + ((((c >> 3) ^ ((lo + 2) & 7))) << 3) + (c & 7);
    int wo3 = (lo + 3) * 64 + ((((c >> 3) ^ ((lo + 3) & 7))) << 3) + (c & 7);
    size_t ho0 = ((size_t)(b0 + lo + 0) * SS) * 64 + c;
    size_t ho1 = ((size_t)(b0 + lo + 1) * SS) * 64 + c;
    size_t ho2 = ((size_t)(b0 + lo + 2) * SS) * 64 + c;
    size_t ho3 = ((size_t)(b0 + lo + 3) * SS) * 64 + c;

    // prologue: depth-2 prefetch (sets A=t0, B=t1)
    float4 axr = *(const float4*)&xg[((size_t)0 * 192 + c) * 16 + lo];
    float4 axz = *(const float4*)&xg[((size_t)0 * 192 + 64 + c) * 16 + lo];
    float4 axn = *(const float4*)&xg[((size_t)0 * 192 + 128 + c) * 16 + lo];
    float4 bxr = *(const float4*)&xg[((size_t)1 * 192 + c) * 16 + lo];
    float4 bxz = *(const float4*)&xg[((size_t)1 * 192 + 64 + c) * 16 + lo];
    float4 bxn = *(const float4*)&xg[((size_t)1 * 192 + 128 + c) * 16 + lo];
    __syncthreads();   // wl + hb[0] visible (one-time full barrier is fine)

    int cur = 0;
    auto step = [&](float4 xr4, float4 xz4, float4 xn4, int t) {
        f32x4 ar = {br_, br_, br_, br_};
        f32x4 az = {bz_, bz_, bz_, bz_};
        f32x4 an = {bn_, bn_, bn_, bn_};
#pragma unroll
        for (int ks = 0; ks < 2; ++ks) {
            int soff = (((ks << 2) + hi) ^ (fr & 7)) << 3;
            short8 af  = *(const short8*)&hb[cur][fr * 64 + soff];
            short8 wfr = *(const short8*)&wl[g0 * 64 + soff];
            short8 wfz = *(const short8*)&wl[g1 * 64 + soff];
            short8 wfn = *(const short8*)&wl[g2 * 64 + soff];
            ar = __builtin_amdgcn_mfma_f32_16x16x32_bf16(af, wfr, ar, 0, 0, 0);
            az = __builtin_amdgcn_mfma_f32_16x16x32_bf16(af, wfz, az, 0, 0, 0);
            an = __builtin_amdgcn_mfma_f32_16x16x32_bf16(af, wfn, an, 0, 0, 0);
        }
        hr0 = gru_gate(xr4.x, xz4.x, xn4.x, ar[0], az[0], an[0], hr0);
        hr1 = gru_gate(xr4.y, xz4.y, xn4.y, ar[1], az[1], an[1], hr1);
        hr2 = gru_gate(xr4.z, xz4.z, xn4.z, ar[2], az[2], an[2], hr2);
        hr3 = gru_gate(xr4.w, xz4.w, xn4.w, ar[3], az[3], an[3], hr3);
        u16 v0 = f2b(hr0), v1 = f2b(hr1), v2 = f2b(hr2), v3 = f2b(hr3);
        int nxt = cur ^ 1;
        hb[nxt][wo0] = v0; hb[nxt][wo1] = v1; hb[nxt][wo2] = v2; hb[nxt][wo3] = v3;
        hsb[ho0 + (size_t)t * 64] = v0;
        hsb[ho1 + (size_t)t * 64] = v1;
        hsb[ho2 + (size_t)t * 64] = v2;
        hsb[ho3 + (size_t)t * 64] = v3;
        // LDS-only drain + raw barrier: global prefetch loads stay in flight
        asm volatile("s_waitcnt lgkmcnt(0)\n\ts_barrier" ::: "memory");
        cur = nxt;
    };

    for (int t = 0; t < SS; t += 2) {
        {   // even step: consume A, refill A for t+2
            int tp = (t + 2 < SS) ? t + 2 : t;
            float4 nr = *(const float4*)&xg[((size_t)tp * 192 + c) * 16 + lo];
            float4 nz = *(const float4*)&xg[((size_t)tp * 192 + 64 + c) * 16 + lo];
            float4 nn = *(const float4*)&xg[((size_t)tp * 192 + 128 + c) * 16 + lo];
            step(axr, axz, axn, t);
            axr = nr; axz = nz; axn = nn;
        }
        {   // odd step: consume B, refill B for t+3
            int tp = (t + 3 < SS) ? t + 3 : t + 1;
            float4 nr = *(const float4*)&xg[((size_t)tp * 192 + c) * 16 + lo];
            float4 nz = *(const float4*)&xg[((size_t)tp * 192 + 64 + c) * 16 + lo];
            float4 nn = *(const float4*)&xg[((size_t)tp * 192 + 128 + c) * 16 + lo];
            step(bxr, bxz, bxn, t + 1);
            bxr = nr; bxz = nz; bxn = nn;
        }
    }
}

// ---------------------------------------------------------------- bf16 MFMA GEMM (BK=64, swizzled)
// MODE: 1=f32 C, 2=bf16 Cb, 3=both, 4=fused residual+LayerNorm (N==128, bn==0)
__device__ __forceinline__ void gl_lds16(const void* g, void* s) {
    __builtin_amdgcn_global_load_lds(
        (const __attribute__((address_space(1))) void*)g,
        (__attribute__((address_space(3))) void*)s, 16, 0, 0);
}

template <int MODE, bool RELU>
__global__ __launch_bounds__(256, 2) void mfma_gemm(const u16* __restrict__ A,
                                                    const u16* __restrict__ W,
                                                    const float* __restrict__ bias,
                                                    float* __restrict__ C,
                                                    u16* __restrict__ Cb,
                                                    const float* __restrict__ lns,
                                                    const float* __restrict__ lnb,
                                                    int M, int N, int K) {
    __shared__ __align__(16) u16 Al[128 * 64];
    __shared__ __align__(16) u16 Bl[128 * 64];
    __shared__ float lred[2][2][128];
    int bm = blockIdx.x, bn = blockIdx.y;
    int tid = threadIdx.x;
    int w = tid >> 6, lane = tid & 63;
    int wrow = (w >> 1) * 64, wcol = (w & 1) * 64;
    int fr = lane & 15, hi = lane >> 4;
    int rl = lane >> 3;
    int sl = lane & 7;
    int ssl = sl ^ rl;

    const u16* Ag = A + ((size_t)bm * 128) * K + ssl * 8;
    const u16* Wg = W + ((size_t)bn * 128) * K + ssl * 8;

    f32x4 acc[4][4];
#pragma unroll
    for (int i = 0; i < 4; ++i)
#pragma unroll
        for (int jj = 0; jj < 4; ++jj) acc[i][jj] = (f32x4){0.f, 0.f, 0.f, 0.f};

    int ar[4], br[4];
#pragma unroll
    for (int m = 0; m < 4; ++m) {
        ar[m] = (wrow + m * 16 + fr) * 64;
        br[m] = (wcol + m * 16 + fr) * 64;
    }
    int swz = (fr & 7);

    for (int kt = 0; kt < K; kt += 64) {
        __syncthreads();
#pragma unroll
        for (int i = 0; i < 4; ++i) {
            int c = w * 4 + i;
            int row = c * 8 + rl;
            gl_lds16(Ag + (size_t)row * K + kt, &Al[c * 512]);
            gl_lds16(Wg + (size_t)row * K + kt, &Bl[c * 512]);
        }
        __syncthreads();
#pragma unroll
        for (int kk = 0; kk < 2; ++kk) {
            short8 a[4], bq[4];
            int soff = (((kk << 2) + hi) ^ swz) << 3;
#pragma unroll
            for (int m = 0; m < 4; ++m)
                a[m] = *(const short8*)&Al[ar[m] + soff];
#pragma unroll
            for (int n = 0; n < 4; ++n)
                bq[n] = *(const short8*)&Bl[br[n] + soff];
#pragma unroll
            for (int m = 0; m < 4; ++m)
#pragma unroll
                for (int n = 0; n < 4; ++n)
                    acc[m][n] = __builtin_amdgcn_mfma_f32_16x16x32_bf16(a[m], bq[n], acc[m][n], 0, 0, 0);
        }
    }

    float bv[4];
#pragma unroll
    for (int n = 0; n < 4; ++n) bv[n] = bias[bn * 128 + wcol + n * 16 + fr];

    if (MODE == 4) {
        float v[4][4][4];
#pragma unroll
        for (int m = 0; m < 4; ++m)
#pragma unroll
            for (int j = 0; j < 4; ++j) {
                int row = bm * 128 + wrow + m * 16 + hi * 4 + j;
#pragma unroll
                for (int n = 0; n < 4; ++n)
                    v[m][n][j] = acc[m][n][j] + bv[n] + C[(size_t)row * 128 + wcol + n * 16 + fr];
            }
#pragma unroll
        for (int m = 0; m < 4; ++m)
#pragma unroll
            for (int j = 0; j < 4; ++j) {
                float s = v[m][0][j] + v[m][1][j] + v[m][2][j] + v[m][3][j];
                float q = v[m][0][j]*v[m][0][j] + v[m][1][j]*v[m][1][j]
                        + v[m][2][j]*v[m][2][j] + v[m][3][j]*v[m][3][j];
#pragma unroll
                for (int off = 1; off <= 8; off <<= 1) {
                    s += __shfl_xor(s, off);
                    q += __shfl_xor(q, off);
                }
                if (fr == 0) {
                    int lrow = wrow + m * 16 + hi * 4 + j;
                    lred[0][w & 1][lrow] = s;
                    lred[1][w & 1][lrow] = q;
                }
            }
        __syncthreads();
        float sv[4], bb[4];
#pragma unroll
        for (int n = 0; n < 4; ++n) {
            sv[n] = lns[wcol + n * 16 + fr];
            bb[n] = lnb[wcol + n * 16 + fr];
        }
#pragma unroll
        for (int m = 0; m < 4; ++m)
#pragma unroll
            for (int j = 0; j < 4; ++j) {
                int lrow = wrow + m * 16 + hi * 4 + j;
                float mean = (lred[0][0][lrow] + lred[0][1][lrow]) * (1.f / 128.f);
                float msq  = (lred[1][0][lrow] + lred[1][1][lrow]) * (1.f / 128.f);
                float rstd = rsqrtf(msq - mean * mean + 1e-5f);
                int row = bm * 128 + lrow;
#pragma unroll
                for (int n = 0; n < 4; ++n) {
                    int col = wcol + n * 16 + fr;
                    float o = (v[m][n][j] - mean) * rstd * sv[n] + bb[n];
                    C[(size_t)row * 128 + col] = o;
                    Cb[(size_t)row * 128 + col] = f2b(o);
                }
            }
    } else {
#pragma unroll
        for (int m = 0; m < 4; ++m) {
#pragma unroll
            for (int j = 0; j < 4; ++j) {
                int row = bm * 128 + wrow + m * 16 + hi * 4 + j;
#pragma unroll
                for (int n = 0; n < 4; ++n) {
                    int col = bn * 128 + wcol + n * 16 + fr;
                    float vv = acc[m][n][j] + bv[n];
                    if (RELU) vv = fmaxf(vv, 0.f);
                    if (MODE & 1) C[(size_t)row * N + col] = vv;
                    if (MODE & 2) Cb[(size_t)row * N + col] = f2b(vv);
                }
            }
        }
    }
}

// ---------------------------------------------------------------- fused FF: relu(zb@W1^T+b1)@W2^T+b2
// + residual + LN2, one block per 128 rows (grid 256 = 1 block/CU), no global ff buffer.
__global__ __launch_bounds__(256, 1) void ff_fused_kernel(const u16* __restrict__ zbin,
                                                          const u16* __restrict__ w1,
                                                          const float* __restrict__ b1,
                                                          const u16* __restrict__ w2,
                                                          const float* __restrict__ b2,
                                                          const float* __restrict__ lns,
                                                          const float* __restrict__ lnb,
                                                          float* __restrict__ z,
                                                          u16* __restrict__ zbout) {
    __shared__ __align__(16) u16 ZB[2][128 * 64];
    __shared__ __align__(16) u16 W1C[2][128 * 64];
    __shared__ __align__(16) u16 W2C[2][128 * 64];
    __shared__ __align__(16) u16 A1[2][128 * 64];
    __shared__ float lred[2][2][128];
    int bm = blockIdx.x;
    int tid = threadIdx.x;
    int w = tid >> 6, lane = tid & 63;
    int wrow = (w >> 1) * 64, wcol = (w & 1) * 64;
    int fr = lane & 15, hi = lane >> 4;
    int rl = lane >> 3, ssl = (lane & 7) ^ rl;
    int swz = fr & 7;
    int xh = wrow >> 6;

#pragma unroll
    for (int hk = 0; hk < 2; ++hk)
#pragma unroll
        for (int i = 0; i < 4; ++i) {
            int ch = w * 4 + i, row = ch * 8 + rl;
            gl_lds16(zbin + ((size_t)(bm * 128 + row)) * 128 + hk * 64 + ssl * 8, &ZB[hk][ch * 512]);
        }

    f32x4 acc2[4][4];
#pragma unroll
    for (int m = 0; m < 4; ++m)
#pragma unroll
        for (int n = 0; n < 4; ++n) acc2[m][n] = (f32x4){0.f, 0.f, 0.f, 0.f};

    for (int ci = 0; ci < 16; ++ci) {
#pragma unroll
        for (int hk = 0; hk < 2; ++hk)
#pragma unroll
            for (int i = 0; i < 4; ++i) {
                int ch = w * 4 + i, row = ch * 8 + rl;
                gl_lds16(w1 + ((size_t)(ci * 128 + row)) * 128 + hk * 64 + ssl * 8, &W1C[hk][ch * 512]);
                gl_lds16(w2 + ((size_t)row) * 2048 + ci * 128 + hk * 64 + ssl * 8, &W2C[hk][ch * 512]);
            }
        __syncthreads();

        f32x4 acc1[4][4];
#pragma unroll
        for (int m = 0; m < 4; ++m)
#pragma unroll
            for (int n = 0; n < 4; ++n) acc1[m][n] = (f32x4){0.f, 0.f, 0.f, 0.f};
#pragma unroll
        for (int ks = 0; ks < 4; ++ks) {
            int hk = ks >> 1;
            int soff = ((((ks & 1) << 2) + hi) ^ swz) << 3;
            short8 a[4], b[4];
#pragma unroll
            for (int m = 0; m < 4; ++m)
                a[m] = *(const short8*)&W1C[hk][(wrow + m * 16 + fr) * 64 + soff];
#pragma unroll
            for (int n = 0; n < 4; ++n)
                b[n] = *(const short8*)&ZB[hk][(wcol + n * 16 + fr) * 64 + soff];
#pragma unroll
            for (int m = 0; m < 4; ++m)
#pragma unroll
                for (int n = 0; n < 4; ++n)
                    acc1[m][n] = __builtin_amdgcn_mfma_f32_16x16x32_bf16(a[m], b[n], acc1[m][n], 0, 0, 0);
        }
#pragma unroll
        for (int m = 0; m < 4; ++m) {
            int x0 = wrow + m * 16 + hi * 4;
            float4 bb = *(const float4*)&b1[ci * 128 + x0];
            int slot = (x0 & 63) >> 3;
            int wadd = x0 & 7;
#pragma unroll
            for (int n = 0; n < 4; ++n) {
                int r = wcol + n * 16 + fr;
                float v0 = fmaxf(acc1[m][n][0] + bb.x, 0.f);
                float v1 = fmaxf(acc1[m][n][1] + bb.y, 0.f);
                float v2 = fmaxf(acc1[m][n][2] + bb.z, 0.f);
                float v3 = fmaxf(acc1[m][n][3] + bb.w, 0.f);
                uint2 pk;
                pk.x = (unsigned)f2b(v0) | ((unsigned)f2b(v1) << 16);
                pk.y = (unsigned)f2b(v2) | ((unsigned)f2b(v3) << 16);
                *(uint2*)&A1[xh][r * 64 + ((slot ^ (r & 7)) << 3) + wadd] = pk;
            }
        }
        __syncthreads();

#pragma unroll
        for (int ks = 0; ks < 4; ++ks) {
            int hk = ks >> 1;
            int soff = ((((ks & 1) << 2) + hi) ^ swz) << 3;
            short8 a[4], b[4];
#pragma unroll
            for (int m = 0; m < 4; ++m)
                a[m] = *(const short8*)&W2C[hk][(wrow + m * 16 + fr) * 64 + soff];
#pragma unroll
            for (int n = 0; n < 4; ++n)
                b[n] = *(const short8*)&A1[hk][(wcol + n * 16 + fr) * 64 + soff];
#pragma unroll
            for (int m = 0; m < 4; ++m)
#pragma unroll
                for (int n = 0; n < 4; ++n)
                    acc2[m][n] = __builtin_amdgcn_mfma_f32_16x16x32_bf16(a[m], b[n], acc2[m][n], 0, 0, 0);
        }
        __syncthreads();
    }

    float vv[4][4][4];
#pragma unroll
    for (int m = 0; m < 4; ++m) {
        int x0 = wrow + m * 16 + hi * 4;
        float4 bb = *(const float4*)&b2[x0];
#pragma unroll
        for (int n = 0; n < 4; ++n) {
            int y = wcol + n * 16 + fr;
            float4 zo = *(const float4*)&z[((size_t)(bm * 128 + y)) * 128 + x0];
            vv[m][n][0] = acc2[m][n][0] + bb.x + zo.x;
            vv[m][n][1] = acc2[m][n][1] + bb.y + zo.y;
            vv[m][n][2] = acc2[m][n][2] + bb.z + zo.z;
            vv[m][n][3] = acc2[m][n][3] + bb.w + zo.w;
        }
    }
#pragma unroll
    for (int n = 0; n < 4; ++n) {
        float s = 0.f, q = 0.f;
#pragma unroll
        for (int m = 0; m < 4; ++m)
#pragma unroll
            for (int j = 0; j < 4; ++j) { float v = vv[m][n][j]; s += v; q += v * v; }
        s += __shfl_xor(s, 16); s += __shfl_xor(s, 32);
        q += __shfl_xor(q, 16); q += __shfl_xor(q, 32);
        if (hi == 0) {
            int y = wcol + n * 16 + fr;
            lred[0][xh][y] = s;
            lred[1][xh][y] = q;
        }
    }
    __syncthreads();
#pragma unroll
    for (int n = 0; n < 4; ++n) {
        int y = wcol + n * 16 + fr;
        float mean = (lred[0][0][y] + lred[0][1][y]) * (1.f / 128.f);
        float msq  = (lred[1][0][y] + lred[1][1][y]) * (1.f / 128.f);
        float rstd = rsqrtf(msq - mean * mean + 1e-5f);
#pragma unroll
        for (int m = 0; m < 4; ++m) {
            int x0 = wrow + m * 16 + hi * 4;
            float4 sv = *(const float4*)&lns[x0];
            float4 bv = *(const float4*)&lnb[x0];
            float o0 = (vv[m][n][0] - mean) * rstd * sv.x + bv.x;
            float o1 = (vv[m][n][1] - mean) * rstd * sv.y + bv.y;
            float o2 = (vv[m][n][2] - mean) * rstd * sv.z + bv.z;
            float o3 = (vv[m][n][3] - mean) * rstd * sv.w + bv.w;
            size_t zoff = ((size_t)(bm * 128 + y)) * 128 + x0;
            *(float4*)&z[zoff] = (float4){o0, o1, o2, o3};
            uint2 pk;
            pk.x = (unsigned)f2b(o0) | ((unsigned)f2b(o1) << 16);
            pk.y = (unsigned)f2b(o2) | ((unsigned)f2b(o3) << 16);
            *(uint2*)&zbout[zoff] = pk;
        }
    }
}

// ---------------------------------------------------------------- attention (bf16 qkv in, bf16 out)
__global__ __launch_bounds__(256) void attn_kernel(const u16* __restrict__ qkv,
                                                   const float* __restrict__ tm,
                                                   u16* __restrict__ attno) {
    int bh = blockIdx.x;
    int b = bh / NHH, hd = bh % NHH;
    int s = threadIdx.x;

    __shared__ float Kt[64][32];
    __shared__ float Vt[64][32];
    __shared__ float tms[64];

    float q[32];
    const u16* qrow = qkv + ((size_t)b * SS + s) * 384 + hd * 32;
#pragma unroll
    for (int j = 0; j < 32; j += 8) {
        short8 v = *(const short8*)&qrow[j];
#pragma unroll
        for (int jj = 0; jj < 8; ++jj) q[j + jj] = b2f((u16)v[jj]);
    }
    const float scale = 0.17677669529663687f;
    float denom = 0.f;
    float o[32];
#pragma unroll
    for (int j = 0; j < 32; ++j) o[j] = 0.f;

    for (int kt = 0; kt < SS; kt += 64) {
        __syncthreads();
        {
            int r = s >> 2, c = (s & 3) * 8;
            const u16* kb = qkv + ((size_t)b * SS + kt + r) * 384 + 128 + hd * 32 + c;
            const u16* vb = qkv + ((size_t)b * SS + kt + r) * 384 + 256 + hd * 32 + c;
            short8 kv = *(const short8*)kb;
            short8 vvv = *(const short8*)vb;
#pragma unroll
            for (int jj = 0; jj < 8; ++jj) {
                Kt[r][c + jj] = b2f((u16)kv[jj]);
                Vt[r][c + jj] = b2f((u16)vvv[jj]);
            }
        }
        if (s < 64) tms[s] = tm[b * SS + kt + s];
        __syncthreads();
        for (int k = 0; k < 64; ++k) {
            float acc = 0.f;
#pragma unroll
            for (int j = 0; j < 32; ++j) acc += q[j] * Kt[k][j];
            float sc = acc * scale + (tms[k] > 0.f ? 0.f : NEGV);
            float e = __expf(sc);
            denom += e;
#pragma unroll
            for (int j = 0; j < 32; ++j) o[j] += e * Vt[k][j];
        }
    }
    float inv = 1.f / denom;
    u16* orow = attno + ((size_t)b * SS + s) * DD + hd * 32;
#pragma unroll
    for (int j = 0; j < 32; j += 8) {
        short8 ov;
#pragma unroll
        for (int jj = 0; jj < 8; ++jj) ov[jj] = (short)f2b(o[j + jj] * inv);
        *(short8*)&orow[j] = ov;
    }
}

// ---------------------------------------------------------------- score = z @ score_w^T + b (masked)
__global__ __launch_bounds__(256) void score_kernel(const float* __restrict__ z,
                                                    const float* __restrict__ score_w,
                                                    const float* __restrict__ score_b,
                                                    const float* __restrict__ tm,
                                                    float* __restrict__ scores) {
    int row = blockIdx.x * 64 + (threadIdx.x >> 2);
    int c = threadIdx.x & 3;
    const float* zr = z + (size_t)row * DD + c * 32;
    const float* wr = score_w + c * 32;
    float acc = 0.f;
#pragma unroll
    for (int j = 0; j < 32; j += 4) {
        float4 a = *(const float4*)(zr + j), w = *(const float4*)(wr + j);
        acc += a.x * w.x + a.y * w.y + a.z * w.z + a.w * w.w;
    }
    acc += __shfl_xor(acc, 1);
    acc += __shfl_xor(acc, 2);
    if (c == 0) {
        float sc = acc + score_b[0];
        scores[row] = (tm[row] > 0.f) ? sc : NEGV;
    }
}

// ---------------------------------------------------------------- softmax over S + weighted pool
__global__ __launch_bounds__(256) void pool_kernel(const float* __restrict__ z,
                                                   const float* __restrict__ scores,
                                                   float* __restrict__ pooled) {
    int b = blockIdx.x;
    int tid = threadIdx.x;
    __shared__ float al[SS];
    __shared__ float red[8];
    __shared__ float pp[2][128];

    float sc = scores[b * SS + tid];
    float m = sc;
#pragma unroll
    for (int off = 32; off; off >>= 1) m = fmaxf(m, __shfl_xor(m, off));
    if ((tid & 63) == 0) red[tid >> 6] = m;
    __syncthreads();
    m = fmaxf(fmaxf(red[0], red[1]), fmaxf(red[2], red[3]));
    float e = __expf(sc - m);
    float ssum = e;
#pragma unroll
    for (int off = 32; off; off >>= 1) ssum += __shfl_xor(ssum, off);
    if ((tid & 63) == 0) red[4 + (tid >> 6)] = ssum;
    __syncthreads();
    ssum = red[4] + red[5] + red[6] + red[7];
    al[tid] = e / ssum;
    __syncthreads();

    int d = tid & 127, half = tid >> 7;
    float acc = 0.f;
    for (int t = half; t < SS; t += 2) acc += al[t] * z[((size_t)b * SS + t) * DD + d];
    pp[half][d] = acc;
    __syncthreads();
    if (tid < 128) pooled[b * 128 + tid] = pp[0][tid] + pp[1][tid];
}

// ---------------------------------------------------------------- routed heads
__global__ __launch_bounds__(128) void head_kernel(const float* __restrict__ pooled,
                                                   const float* __restrict__ reg_w,
                                                   const float* __restrict__ reg_b,
                                                   const float* __restrict__ bin_w,
                                                   const float* __restrict__ bin_b,
                                                   const int* __restrict__ wid,
                                                   float* __restrict__ out) {
    int b = blockIdx.x, tid = threadIdx.x;
    __shared__ float p[128];
    p[tid] = pooled[b * 128 + tid];
    __syncthreads();
    if (tid < 9) {
        int w = wid[b];
        const float* wrow;
        float bias;
        if (tid < 8) { wrow = reg_w + ((size_t)w * 8 + tid) * 128; bias = reg_b[w * 8 + tid]; }
        else         { wrow = bin_w + (size_t)w * 128;             bias = bin_b[w]; }
        float acc = bias;
        for (int k = 0; k < 128; ++k) acc += wrow[k] * p[k];
        if (tid < 8) out[b * 8 + tid] = acc;
        else         out[1024 + b] = acc;
    }
}

// ================================================================ host
extern "C" void kernel_launch(void* const* d_in, const int* in_sizes, int n_in,
                              void* d_out, int out_size, void* d_ws, size_t ws_size,
                              hipStream_t stream) {
    const float* x         = (const float*)d_in[0];
    const float* mask      = (const float*)d_in[1];
    const float* delta     = (const float*)d_in[2];
    const float* gru_w_ih  = (const float*)d_in[3];
    const float* gru_w_hh  = (const float*)d_in[4];
    const float* gru_b_ih  = (const float*)d_in[5];
    const float* gru_b_hh  = (const float*)d_in[6];
    const float* dm_w      = (const float*)d_in[7];
    const float* dm_b      = (const float*)d_in[8];
    const float* in_proj_w = (const float*)d_in[9];
    const float* in_proj_b = (const float*)d_in[10];
    const float* out_proj_w= (const float*)d_in[11];
    const float* out_proj_b= (const float*)d_in[12];
    const float* lin1_w    = (const float*)d_in[13];
    const float* lin1_b    = (const float*)d_in[14];
    const float* lin2_w    = (const float*)d_in[15];
    const float* lin2_b    = (const float*)d_in[16];
    const float* ln1_s     = (const float*)d_in[17];
    const float* ln1_bb    = (const float*)d_in[18];
    const float* ln2_s     = (const float*)d_in[19];
    const float* ln2_bb    = (const float*)d_in[20];
    const float* score_w   = (const float*)d_in[21];
    const float* score_b   = (const float*)d_in[22];
    const float* reg_w     = (const float*)d_in[23];
    const float* reg_b     = (const float*)d_in[24];
    const float* bin_w     = (const float*)d_in[25];
    const float* bin_b     = (const float*)d_in[26];
    const int*   window_id = (const int*)d_in[27];
    float* out = (float*)d_out;

    char* w8 = (char*)d_ws;
    float* z      = (float*)(w8 + 0);            // 16,777,216
    u16*   zb     = (u16*)  (w8 + 16777216);     //  8,388,608
    u16*   hsb    = (u16*)  (w8 + 25165824);     //  4,194,304
    u16*   wb_dm  = (u16*)  (w8 + 29360128);     //     16,384
    u16*   wb_ip  = (u16*)  (w8 + 29376512);     //    196,608
    u16*   wb_op  = (u16*)  (w8 + 29573120);     //     65,536
    u16*   wb_l1  = (u16*)  (w8 + 29638656);     //  1,048,576
    u16*   wb_l2  = (u16*)  (w8 + 30687232);     //  1,048,576
    float* tm     = (float*)(w8 + 31735808);     //    131,072
    float* scores = (float*)(w8 + 31866880);     //    131,072
    float* pooled = (float*)(w8 + 31997952);     //     65,536
    float* xwt    = (float*)(w8 + 32063488);     // 25,165,824 (GRU: xwt fp32 | later: qkvb bf16)
    u16*   qkvb   = (u16*)  (w8 + 32063488);
    u16*   attnob = (u16*)  (w8 + 57229312);     //  8,388,608   (total ~65.6MB)

    cvt_all_kernel<<<580, 256, 0, stream>>>(dm_w, in_proj_w, out_proj_w, lin1_w, lin2_w,
                                            wb_dm, wb_ip, wb_op, wb_l1, wb_l2);

    tm_kernel<<<(BB * SS + 255) / 256, 256, 0, stream>>>(mask, tm);
    xw_kernel<<<2048, 192, 0, stream>>>(x, mask, delta, gru_w_ih, gru_b_ih, xwt);
    gru_scan_kernel<<<8, 256, 0, stream>>>(gru_w_hh, gru_b_hh, xwt, hsb);

    mfma_gemm<3, false><<<dim3(256, 1), 256, 0, stream>>>(
        hsb, wb_dm, dm_b, z, zb, nullptr, nullptr, 32768, 128, 64);

    for (int l = 0; l < LL; ++l) {
        mfma_gemm<2, false><<<dim3(256, 3), 256, 0, stream>>>(
            zb, wb_ip + (size_t)l * 49152, in_proj_b + l * 384, nullptr, qkvb,
            nullptr, nullptr, 32768, 384, 128);
        attn_kernel<<<BB * NHH, 256, 0, stream>>>(qkvb, tm, attnob);
        mfma_gemm<4, false><<<dim3(256, 1), 256, 0, stream>>>(
            attnob, wb_op + (size_t)l * 16384, out_proj_b + l * 128, z, zb,
            ln1_s + l * 128, ln1_bb + l * 128, 32768, 128, 128);
        ff_fused_kernel<<<256, 256, 0, stream>>>(
            zb, wb_l1 + (size_t)l * 262144, lin1_b + l * 2048,
            wb_l2 + (size_t)l * 262144, lin2_b + l * 128,
            ln2_s + l * 128, ln2_bb + l * 128, z, zb);
    }

    score_kernel<<<BB * SS / 64, 256, 0, stream>>>(z, score_w, score_b, tm, scores);
    pool_kernel<<<BB, 256, 0, stream>>>(z, scores, pooled);
    head_kernel<<<BB, 128, 0, stream>>>(pooled, reg_w, reg_b, bin_w, bin_b, window_id, out);
}